// Round 1
// baseline (2154.207 us; speedup 1.0000x reference)
//
#include <hip/hip_runtime.h>
#include <hip/hip_bf16.h>

// Problem: B=4, T=2048, C=1024, H=16, D=64. fp32 in/out.
// Pipeline: qkv_proj (GEMM -> bf16 q/k/v in ws) -> attn (flash, fp32 LDS) -> out_proj (GEMM+bias).

#define B_ 4
#define T_ 2048
#define C_ 1024
#define H_ 16
#define D_ 64

typedef unsigned short ushort8 __attribute__((ext_vector_type(8)));

__device__ __forceinline__ float bf2f(unsigned short u) {
    return __uint_as_float((unsigned)u << 16);
}

// ---------------- QKV projection: [8192 x 1024] @ [1024 x 64] per (head, {q,k,v}) ----------------
__global__ __launch_bounds__(256) void qkv_proj(const float* __restrict__ x,
                                                const float* __restrict__ Wq,
                                                const float* __restrict__ Wk,
                                                const float* __restrict__ Wv,
                                                __hip_bfloat16* __restrict__ q,
                                                __hip_bfloat16* __restrict__ k,
                                                __hip_bfloat16* __restrict__ v) {
    __shared__ float As[16][68];   // [k][m], pad 68: compute reads conflict-free
    __shared__ float Bs[16][64];   // [k][n]
    const int tid = threadIdx.x;
    const int m0  = blockIdx.x * 64;
    const int z   = blockIdx.y;              // 0..47
    const int which = z / H_;                // 0=q 1=k 2=v (block-uniform)
    const int h     = z % H_;
    const float* W = (which == 0 ? Wq : which == 1 ? Wk : Wv) + (size_t)h * C_ * D_;
    __hip_bfloat16* out = (which == 0 ? q : which == 1 ? k : v);

    const int ty = tid >> 4, tx = tid & 15;
    float acc[4][4] = {};

    for (int k0 = 0; k0 < C_; k0 += 16) {
        {   // A tile 64x16, float4 per thread
            int arow = tid >> 2;
            int acol = (tid & 3) * 4;
            float4 a = *reinterpret_cast<const float4*>(&x[(size_t)(m0 + arow) * C_ + k0 + acol]);
            As[acol + 0][arow] = a.x; As[acol + 1][arow] = a.y;
            As[acol + 2][arow] = a.z; As[acol + 3][arow] = a.w;
        }
        {   // B tile 16x64, float4 per thread
            int brow = tid >> 4;
            int bcol = (tid & 15) * 4;
            float4 b = *reinterpret_cast<const float4*>(&W[(size_t)(k0 + brow) * D_ + bcol]);
            *reinterpret_cast<float4*>(&Bs[brow][bcol]) = b;
        }
        __syncthreads();
        #pragma unroll
        for (int kk = 0; kk < 16; ++kk) {
            float a[4], b[4];
            #pragma unroll
            for (int i = 0; i < 4; ++i) a[i] = As[kk][ty * 4 + i];
            #pragma unroll
            for (int j = 0; j < 4; ++j) b[j] = Bs[kk][tx * 4 + j];
            #pragma unroll
            for (int i = 0; i < 4; ++i)
                #pragma unroll
                for (int j = 0; j < 4; ++j)
                    acc[i][j] += a[i] * b[j];
        }
        __syncthreads();
    }
    #pragma unroll
    for (int i = 0; i < 4; ++i) {
        int m = m0 + ty * 4 + i;
        int b = m / T_, t = m % T_;
        size_t base = ((size_t)(b * H_ + h) * T_ + t) * D_ + tx * 4;
        #pragma unroll
        for (int j = 0; j < 4; ++j) out[base + j] = __float2bfloat16(acc[i][j]);
    }
}

// ---------------- Flash attention: block = (b*h, 64-row Q tile), 256 thr = 4 thr/row ----------------
__global__ __launch_bounds__(256) void attn(const __hip_bfloat16* __restrict__ q,
                                            const __hip_bfloat16* __restrict__ k,
                                            const __hip_bfloat16* __restrict__ v,
                                            float* __restrict__ o) {
    __shared__ float Qs[64][68];   // [row][d]   (pre-scaled by 1/32)
    __shared__ float KtS[64][68];  // [d][s]  -- transposed so score reads are 2-way max
    __shared__ float Vs[64][68];   // [s][d]
    __shared__ float Ps[64][68];   // [row][s]
    const int tid = threadIdx.x;
    const int q0  = blockIdx.x * 64;
    const int bh  = blockIdx.y;
    const size_t base = (size_t)bh * T_ * D_;

    // load Q tile (64x64 bf16), scale folded in
    for (int c = tid; c < 512; c += 256) {
        int row = c >> 3, col = (c & 7) * 8;
        ushort8 u = *reinterpret_cast<const ushort8*>(
            reinterpret_cast<const unsigned short*>(q) + base + (size_t)(q0 + row) * D_ + col);
        #pragma unroll
        for (int i = 0; i < 8; ++i) Qs[row][col + i] = bf2f(u[i]) * 0.03125f;  // C^-0.5 = 1/32
    }

    const int r = tid >> 2, g = tid & 3;   // row 0..63, col-group 0..3
    const int qr = q0 + r;
    float m_run = -INFINITY, l_run = 0.f;
    float oacc[16];
    #pragma unroll
    for (int i = 0; i < 16; ++i) oacc[i] = 0.f;

    for (int s0 = 0; s0 <= q0; s0 += 64) {
        __syncthreads();   // prev PV done before overwriting K/V
        for (int c = tid; c < 512; c += 256) {
            int row = c >> 3, col = (c & 7) * 8;
            ushort8 uk = *reinterpret_cast<const ushort8*>(
                reinterpret_cast<const unsigned short*>(k) + base + (size_t)(s0 + row) * D_ + col);
            ushort8 uv = *reinterpret_cast<const ushort8*>(
                reinterpret_cast<const unsigned short*>(v) + base + (size_t)(s0 + row) * D_ + col);
            #pragma unroll
            for (int i = 0; i < 8; ++i) {
                KtS[col + i][row] = bf2f(uk[i]);
                Vs[row][col + i]  = bf2f(uv[i]);
            }
        }
        __syncthreads();

        float s[16];
        #pragma unroll
        for (int j = 0; j < 16; ++j) s[j] = 0.f;
        for (int kk = 0; kk < 64; ++kk) {
            float qv = Qs[r][kk];
            #pragma unroll
            for (int j = 0; j < 16; ++j) s[j] += qv * KtS[kk][g * 16 + j];
        }

        float tmax = -INFINITY;
        #pragma unroll
        for (int j = 0; j < 16; ++j) {
            int sc = s0 + g * 16 + j;
            if (sc > qr) s[j] = -INFINITY;            // causal mask
            tmax = fmaxf(tmax, s[j]);
        }
        tmax = fmaxf(tmax, __shfl_xor(tmax, 1, 4));
        tmax = fmaxf(tmax, __shfl_xor(tmax, 2, 4));
        float mnew  = fmaxf(m_run, tmax);
        float scale = __expf(m_run - mnew);           // first tile: exp(-inf)=0, oacc already 0
        float rsum = 0.f;
        #pragma unroll
        for (int j = 0; j < 16; ++j) {
            float p = __expf(s[j] - mnew);            // masked -> 0
            s[j] = p;
            rsum += p;
        }
        rsum += __shfl_xor(rsum, 1, 4);
        rsum += __shfl_xor(rsum, 2, 4);
        l_run = l_run * scale + rsum;
        m_run = mnew;
        #pragma unroll
        for (int i = 0; i < 16; ++i) oacc[i] *= scale;

        #pragma unroll
        for (int j = 0; j < 16; ++j) Ps[r][g * 16 + j] = s[j];
        __syncthreads();
        for (int ss = 0; ss < 64; ++ss) {
            float pv = Ps[r][ss];
            #pragma unroll
            for (int i = 0; i < 16; ++i) oacc[i] += pv * Vs[ss][g * 16 + i];
        }
    }

    // write o as [B, T, H*D] (heads concatenated)
    int b = bh / H_, h = bh % H_;
    float inv = 1.f / l_run;
    size_t obase = ((size_t)b * T_ + qr) * C_ + h * D_ + g * 16;
    #pragma unroll
    for (int i = 0; i < 16; ++i) o[obase + i] = oacc[i] * inv;
}

// ---------------- Output projection: [8192 x 1024] @ [1024 x 1024] + bias ----------------
__global__ __launch_bounds__(256) void out_proj(const float* __restrict__ o,
                                                const float* __restrict__ Wp,
                                                const float* __restrict__ bp,
                                                float* __restrict__ out) {
    __shared__ float As[16][68];
    __shared__ float Bs[16][64];
    const int tid = threadIdx.x;
    const int m0 = blockIdx.x * 64;
    const int n0 = blockIdx.y * 64;
    const int ty = tid >> 4, tx = tid & 15;
    float acc[4][4] = {};

    for (int k0 = 0; k0 < C_; k0 += 16) {
        {
            int arow = tid >> 2;
            int acol = (tid & 3) * 4;
            float4 a = *reinterpret_cast<const float4*>(&o[(size_t)(m0 + arow) * C_ + k0 + acol]);
            As[acol + 0][arow] = a.x; As[acol + 1][arow] = a.y;
            As[acol + 2][arow] = a.z; As[acol + 3][arow] = a.w;
        }
        {
            int brow = tid >> 4;
            int bcol = (tid & 15) * 4;
            float4 b = *reinterpret_cast<const float4*>(&Wp[(size_t)(k0 + brow) * C_ + n0 + bcol]);
            *reinterpret_cast<float4*>(&Bs[brow][bcol]) = b;
        }
        __syncthreads();
        #pragma unroll
        for (int kk = 0; kk < 16; ++kk) {
            float a[4], b[4];
            #pragma unroll
            for (int i = 0; i < 4; ++i) a[i] = As[kk][ty * 4 + i];
            #pragma unroll
            for (int j = 0; j < 4; ++j) b[j] = Bs[kk][tx * 4 + j];
            #pragma unroll
            for (int i = 0; i < 4; ++i)
                #pragma unroll
                for (int j = 0; j < 4; ++j)
                    acc[i][j] += a[i] * b[j];
        }
        __syncthreads();
    }
    #pragma unroll
    for (int i = 0; i < 4; ++i) {
        int m = m0 + ty * 4 + i;
        #pragma unroll
        for (int j = 0; j < 4; ++j) {
            int n = n0 + tx * 4 + j;
            out[(size_t)m * C_ + n] = acc[i][j] + bp[n];
        }
    }
}

extern "C" void kernel_launch(void* const* d_in, const int* in_sizes, int n_in,
                              void* d_out, int out_size, void* d_ws, size_t ws_size,
                              hipStream_t stream) {
    const float* x  = (const float*)d_in[0];
    const float* Wq = (const float*)d_in[1];
    const float* Wk = (const float*)d_in[2];
    const float* Wv = (const float*)d_in[3];
    const float* Wp = (const float*)d_in[4];
    const float* bp = (const float*)d_in[5];
    float* out = (float*)d_out;

    const size_t qkv_elems = (size_t)B_ * H_ * T_ * D_;     // 8.39M
    __hip_bfloat16* qb = (__hip_bfloat16*)d_ws;
    __hip_bfloat16* kb = qb + qkv_elems;
    __hip_bfloat16* vb = kb + qkv_elems;
    float* ob = (float*)(vb + qkv_elems);                   // 50.3MB offset, 16B aligned

    dim3 gA((B_ * T_) / 64, 3 * H_);
    qkv_proj<<<gA, 256, 0, stream>>>(x, Wq, Wk, Wv, qb, kb, vb);

    dim3 gB(T_ / 64, B_ * H_);
    attn<<<gB, 256, 0, stream>>>(qb, kb, vb, ob);

    dim3 gC((B_ * T_) / 64, C_ / 64);
    out_proj<<<gC, 256, 0, stream>>>(ob, Wp, bp, out);
}

// Round 2
// 1167.771 us; speedup vs baseline: 1.8447x; 1.8447x over previous
//
#include <hip/hip_runtime.h>
#include <hip/hip_bf16.h>

// Problem: B=4, T=2048, C=1024, H=16, D=64. fp32 in/out.
// qkv_proj (fp32 GEMM -> bf16 q/k/v, q pre-scaled by C^-0.5) -> attn (MFMA flash) -> out_proj.

#define B_ 4
#define T_ 2048
#define C_ 1024
#define H_ 16
#define D_ 64

typedef unsigned short u16;
typedef unsigned short ushort8 __attribute__((ext_vector_type(8)));
typedef __attribute__((ext_vector_type(8))) short bf16x8;   // 8 bf16 (4 VGPRs) — MFMA A/B frag
typedef __attribute__((ext_vector_type(4))) float f32x4;    // MFMA C/D frag

__device__ __forceinline__ u16 f2bf(float f) {
    __hip_bfloat16 h = __float2bfloat16(f);
    return *reinterpret_cast<u16*>(&h);
}

// ---------------- QKV projection: [8192 x 1024] @ [1024 x 64] per (head, {q,k,v}) ----------------
__global__ __launch_bounds__(256) void qkv_proj(const float* __restrict__ x,
                                                const float* __restrict__ Wq,
                                                const float* __restrict__ Wk,
                                                const float* __restrict__ Wv,
                                                __hip_bfloat16* __restrict__ q,
                                                __hip_bfloat16* __restrict__ k,
                                                __hip_bfloat16* __restrict__ v) {
    __shared__ float As[16][68];
    __shared__ float Bs[16][64];
    const int tid = threadIdx.x;
    const int m0  = blockIdx.x * 64;
    const int z   = blockIdx.y;              // 0..47
    const int which = z / H_;                // 0=q 1=k 2=v
    const int h     = z % H_;
    const float* W = (which == 0 ? Wq : which == 1 ? Wk : Wv) + (size_t)h * C_ * D_;
    __hip_bfloat16* out = (which == 0 ? q : which == 1 ? k : v);
    const float oscale = (which == 0) ? 0.03125f : 1.0f;   // fold C^-0.5 into q

    const int ty = tid >> 4, tx = tid & 15;
    float acc[4][4] = {};

    for (int k0 = 0; k0 < C_; k0 += 16) {
        {
            int arow = tid >> 2;
            int acol = (tid & 3) * 4;
            float4 a = *reinterpret_cast<const float4*>(&x[(size_t)(m0 + arow) * C_ + k0 + acol]);
            As[acol + 0][arow] = a.x; As[acol + 1][arow] = a.y;
            As[acol + 2][arow] = a.z; As[acol + 3][arow] = a.w;
        }
        {
            int brow = tid >> 4;
            int bcol = (tid & 15) * 4;
            float4 b = *reinterpret_cast<const float4*>(&W[(size_t)(k0 + brow) * D_ + bcol]);
            *reinterpret_cast<float4*>(&Bs[brow][bcol]) = b;
        }
        __syncthreads();
        #pragma unroll
        for (int kk = 0; kk < 16; ++kk) {
            float a[4], b[4];
            #pragma unroll
            for (int i = 0; i < 4; ++i) a[i] = As[kk][ty * 4 + i];
            #pragma unroll
            for (int j = 0; j < 4; ++j) b[j] = Bs[kk][tx * 4 + j];
            #pragma unroll
            for (int i = 0; i < 4; ++i)
                #pragma unroll
                for (int j = 0; j < 4; ++j)
                    acc[i][j] += a[i] * b[j];
        }
        __syncthreads();
    }
    #pragma unroll
    for (int i = 0; i < 4; ++i) {
        int m = m0 + ty * 4 + i;
        int b = m / T_, t = m % T_;
        size_t base = ((size_t)(b * H_ + h) * T_ + t) * D_ + tx * 4;
        #pragma unroll
        for (int j = 0; j < 4; ++j) out[base + j] = __float2bfloat16(acc[i][j] * oscale);
    }
}

// ---------------- MFMA flash attention ----------------
// Block = 4 waves x 64 lanes. blockIdx = (q-tile of 64 rows, b*h).
// Wave w owns Q rows [q0+16w, q0+16w+16). Q A-frags in registers (loaded once).
// K row-major + V transposed in LDS; P re-shaped via per-wave LDS round-trip.
// mfma_f32_16x16x32_bf16: A row=lane&15, k=(lane>>4)*8+i ; C/D col=lane&15, row=(lane>>4)*4+reg.
__global__ __launch_bounds__(256) void attn_mfma(const u16* __restrict__ q,
                                                 const u16* __restrict__ k,
                                                 const u16* __restrict__ v,
                                                 float* __restrict__ o) {
    __shared__ u16 Ks[64][72];      // [s][d]   (pad 8 keeps 16B alignment, breaks bank stride)
    __shared__ u16 Vt[64][72];      // [d][s]
    __shared__ u16 Ps[4][16][72];   // per-wave P tile [qrow][s]

    const int tid  = threadIdx.x;
    const int wid  = tid >> 6;
    const int lane = tid & 63;
    const int l16  = lane & 15;
    const int lq   = lane >> 4;     // 0..3 (k-chunk / row-group selector)
    const int q0   = blockIdx.x * 64;
    const int bh   = blockIdx.y;
    const size_t base = (size_t)bh * T_ * D_;

    // Q A-fragments in registers: rows q0 + wid*16 + l16, k-chunks lq*8 within each 32-slice
    bf16x8 qa[2];
    {
        const u16* qp = q + base + (size_t)(q0 + wid * 16 + l16) * D_;
        qa[0] = *reinterpret_cast<const bf16x8*>(qp + lq * 8);
        qa[1] = *reinterpret_cast<const bf16x8*>(qp + 32 + lq * 8);
    }

    float mrun[4], lrun[4];
    f32x4 oacc[4];                  // [dtile] ; element j = q-row lq*4+j
    #pragma unroll
    for (int j = 0; j < 4; ++j) {
        mrun[j] = -INFINITY; lrun[j] = 0.f;
        oacc[j][0] = 0.f; oacc[j][1] = 0.f; oacc[j][2] = 0.f; oacc[j][3] = 0.f;
    }

    for (int s0 = 0; s0 <= q0; s0 += 64) {
        __syncthreads();            // previous tile's PV reads done
        for (int c = tid; c < 512; c += 256) {
            int row = c >> 3, col8 = (c & 7) * 8;
            ushort8 uk = *reinterpret_cast<const ushort8*>(k + base + (size_t)(s0 + row) * D_ + col8);
            *reinterpret_cast<ushort8*>(&Ks[row][col8]) = uk;
            ushort8 uv = *reinterpret_cast<const ushort8*>(v + base + (size_t)(s0 + row) * D_ + col8);
            #pragma unroll
            for (int i = 0; i < 8; ++i) Vt[col8 + i][row] = uv[i];
        }
        __syncthreads();

        // ---- S = Q K^T : 4 ntiles x 2 kchunks ----
        f32x4 sacc[4];
        #pragma unroll
        for (int nt = 0; nt < 4; ++nt) {
            f32x4 a; a[0] = 0.f; a[1] = 0.f; a[2] = 0.f; a[3] = 0.f;
            #pragma unroll
            for (int kc = 0; kc < 2; ++kc) {
                bf16x8 bk = *reinterpret_cast<const bf16x8*>(&Ks[nt * 16 + l16][kc * 32 + lq * 8]);
                a = __builtin_amdgcn_mfma_f32_16x16x32_bf16(qa[kc], bk, a, 0, 0, 0);
            }
            sacc[nt] = a;
        }

        // ---- causal mask (diagonal tile only) ----
        if (s0 == q0) {
            int rowq = wid * 16 + lq * 4;
            #pragma unroll
            for (int nt = 0; nt < 4; ++nt) {
                int col = nt * 16 + l16;
                #pragma unroll
                for (int j = 0; j < 4; ++j)
                    if (col > rowq + j) sacc[nt][j] = -INFINITY;
            }
        }

        // ---- online softmax: row r = lq*4+j lives in 16-lane group ----
        float pex[4][4];
        #pragma unroll
        for (int j = 0; j < 4; ++j) {
            float tmax = fmaxf(fmaxf(sacc[0][j], sacc[1][j]), fmaxf(sacc[2][j], sacc[3][j]));
            tmax = fmaxf(tmax, __shfl_xor(tmax, 1));
            tmax = fmaxf(tmax, __shfl_xor(tmax, 2));
            tmax = fmaxf(tmax, __shfl_xor(tmax, 4));
            tmax = fmaxf(tmax, __shfl_xor(tmax, 8));
            float mnew = fmaxf(mrun[j], tmax);
            float scl  = __expf(mrun[j] - mnew);
            float rsum = 0.f;
            #pragma unroll
            for (int nt = 0; nt < 4; ++nt) {
                float p = __expf(sacc[nt][j] - mnew);
                pex[nt][j] = p;
                rsum += p;
            }
            rsum += __shfl_xor(rsum, 1);
            rsum += __shfl_xor(rsum, 2);
            rsum += __shfl_xor(rsum, 4);
            rsum += __shfl_xor(rsum, 8);
            lrun[j] = lrun[j] * scl + rsum;
            mrun[j] = mnew;
            #pragma unroll
            for (int dt = 0; dt < 4; ++dt) oacc[dt][j] *= scl;
        }

        // ---- P -> LDS (bf16) to re-shape into A-fragment layout ----
        #pragma unroll
        for (int nt = 0; nt < 4; ++nt)
            #pragma unroll
            for (int j = 0; j < 4; ++j)
                Ps[wid][lq * 4 + j][nt * 16 + l16] = f2bf(pex[nt][j]);
        // per-wave LDS write->read: compiler inserts lgkmcnt ordering (same array)

        // ---- O += P V : 4 dtiles x 2 kchunks ----
        #pragma unroll
        for (int dt = 0; dt < 4; ++dt) {
            #pragma unroll
            for (int kc = 0; kc < 2; ++kc) {
                bf16x8 pa = *reinterpret_cast<const bf16x8*>(&Ps[wid][l16][kc * 32 + lq * 8]);
                bf16x8 vb = *reinterpret_cast<const bf16x8*>(&Vt[dt * 16 + l16][kc * 32 + lq * 8]);
                oacc[dt] = __builtin_amdgcn_mfma_f32_16x16x32_bf16(pa, vb, oacc[dt], 0, 0, 0);
            }
        }
    }

    // ---- epilogue: o[B,T,C] with heads concatenated ----
    const int b = bh / H_, h = bh % H_;
    const int qrow = q0 + wid * 16 + lq * 4;
    #pragma unroll
    for (int j = 0; j < 4; ++j) {
        float inv = 1.f / lrun[j];
        size_t ob = ((size_t)b * T_ + qrow + j) * C_ + h * D_ + l16;
        #pragma unroll
        for (int dt = 0; dt < 4; ++dt)
            o[ob + dt * 16] = oacc[dt][j] * inv;
    }
}

// ---------------- Output projection: [8192 x 1024] @ [1024 x 1024] + bias ----------------
__global__ __launch_bounds__(256) void out_proj(const float* __restrict__ o,
                                                const float* __restrict__ Wp,
                                                const float* __restrict__ bp,
                                                float* __restrict__ out) {
    __shared__ float As[16][68];
    __shared__ float Bs[16][64];
    const int tid = threadIdx.x;
    const int m0 = blockIdx.x * 64;
    const int n0 = blockIdx.y * 64;
    const int ty = tid >> 4, tx = tid & 15;
    float acc[4][4] = {};

    for (int k0 = 0; k0 < C_; k0 += 16) {
        {
            int arow = tid >> 2;
            int acol = (tid & 3) * 4;
            float4 a = *reinterpret_cast<const float4*>(&o[(size_t)(m0 + arow) * C_ + k0 + acol]);
            As[acol + 0][arow] = a.x; As[acol + 1][arow] = a.y;
            As[acol + 2][arow] = a.z; As[acol + 3][arow] = a.w;
        }
        {
            int brow = tid >> 4;
            int bcol = (tid & 15) * 4;
            float4 b = *reinterpret_cast<const float4*>(&Wp[(size_t)(k0 + brow) * C_ + n0 + bcol]);
            *reinterpret_cast<float4*>(&Bs[brow][bcol]) = b;
        }
        __syncthreads();
        #pragma unroll
        for (int kk = 0; kk < 16; ++kk) {
            float a[4], b[4];
            #pragma unroll
            for (int i = 0; i < 4; ++i) a[i] = As[kk][ty * 4 + i];
            #pragma unroll
            for (int j = 0; j < 4; ++j) b[j] = Bs[kk][tx * 4 + j];
            #pragma unroll
            for (int i = 0; i < 4; ++i)
                #pragma unroll
                for (int j = 0; j < 4; ++j)
                    acc[i][j] += a[i] * b[j];
        }
        __syncthreads();
    }
    #pragma unroll
    for (int i = 0; i < 4; ++i) {
        int m = m0 + ty * 4 + i;
        #pragma unroll
        for (int j = 0; j < 4; ++j) {
            int n = n0 + tx * 4 + j;
            out[(size_t)m * C_ + n] = acc[i][j] + bp[n];
        }
    }
}

extern "C" void kernel_launch(void* const* d_in, const int* in_sizes, int n_in,
                              void* d_out, int out_size, void* d_ws, size_t ws_size,
                              hipStream_t stream) {
    const float* x  = (const float*)d_in[0];
    const float* Wq = (const float*)d_in[1];
    const float* Wk = (const float*)d_in[2];
    const float* Wv = (const float*)d_in[3];
    const float* Wp = (const float*)d_in[4];
    const float* bp = (const float*)d_in[5];
    float* out = (float*)d_out;

    const size_t qkv_elems = (size_t)B_ * H_ * T_ * D_;     // 8.39M
    __hip_bfloat16* qb = (__hip_bfloat16*)d_ws;
    __hip_bfloat16* kb = qb + qkv_elems;
    __hip_bfloat16* vb = kb + qkv_elems;
    float* ob = (float*)(vb + qkv_elems);

    dim3 gA((B_ * T_) / 64, 3 * H_);
    qkv_proj<<<gA, 256, 0, stream>>>(x, Wq, Wk, Wv, qb, kb, vb);

    dim3 gB(T_ / 64, B_ * H_);
    attn_mfma<<<gB, 256, 0, stream>>>((const u16*)qb, (const u16*)kb, (const u16*)vb, ob);

    dim3 gC((B_ * T_) / 64, C_ / 64);
    out_proj<<<gC, 256, 0, stream>>>(ob, Wp, bp, out);
}

// Round 3
// 405.360 us; speedup vs baseline: 5.3143x; 2.8808x over previous
//
#include <hip/hip_runtime.h>
#include <hip/hip_bf16.h>

// B=4, T=2048, C=1024, H=16, D=64. fp32 in/out.
// prep: cast x->bf16, transpose+cast weights -> [N][K] bf16 (q-scale folded into Wq)
// qkv_gemm (MFMA 128x128) -> attn (MFMA flash) -> out_gemm (MFMA + bias).

#define B_ 4
#define T_ 2048
#define C_ 1024
#define H_ 16
#define D_ 64
#define M_ (B_*T_)      // 8192

typedef unsigned short u16;
typedef unsigned short ushort8 __attribute__((ext_vector_type(8)));
typedef __attribute__((ext_vector_type(8))) short bf16x8;
typedef __attribute__((ext_vector_type(4))) float f32x4;

__device__ __forceinline__ u16 f2bf(float f) {
    __hip_bfloat16 h = __float2bfloat16(f);
    return *reinterpret_cast<u16*>(&h);
}

__device__ __forceinline__ void gload_lds16(const void* g, void* lds) {
    __builtin_amdgcn_global_load_lds((const __attribute__((address_space(1))) unsigned int*)g,
                                     (__attribute__((address_space(3))) unsigned int*)lds, 16, 0, 0);
}

// ---------------- cast x -> bf16 ----------------
__global__ __launch_bounds__(256) void cast_x(const float* __restrict__ in, u16* __restrict__ out) {
    int i = (blockIdx.x * 256 + threadIdx.x) * 8;
    float4 a = *reinterpret_cast<const float4*>(in + i);
    float4 b = *reinterpret_cast<const float4*>(in + i + 4);
    ushort8 o;
    o[0]=f2bf(a.x); o[1]=f2bf(a.y); o[2]=f2bf(a.z); o[3]=f2bf(a.w);
    o[4]=f2bf(b.x); o[5]=f2bf(b.y); o[6]=f2bf(b.z); o[7]=f2bf(b.w);
    *reinterpret_cast<ushort8*>(out + i) = o;
}

// ---------------- 64x64 transpose+cast tile: out[c][r] = in[r][c]*scale ----------------
__device__ __forceinline__ void ttile64(const float* __restrict__ in, int ldin,
                                        u16* __restrict__ out, int ldout, float scale) {
    __shared__ float t[64][65];
    const int tid = threadIdx.x;
    {
        int c = tid & 63, rr = tid >> 6;
        #pragma unroll
        for (int i = 0; i < 16; ++i) {
            int r = i * 4 + rr;
            t[r][c] = in[(size_t)r * ldin + c];
        }
    }
    __syncthreads();
    {
        int r2 = tid & 63, cg = tid >> 6;
        #pragma unroll
        for (int i = 0; i < 16; ++i) {
            int cc = i * 4 + cg;
            out[(size_t)cc * ldout + r2] = f2bf(t[r2][cc] * scale);
        }
    }
}

// Wt layout: [3072][1024] bf16, row n = which*1024 + h*64 + d, col = c. Wq pre-scaled by 1/32.
__global__ __launch_bounds__(256) void tw_qkv(const float* __restrict__ Wq, const float* __restrict__ Wk,
                                              const float* __restrict__ Wv, u16* __restrict__ Wt) {
    const int z = blockIdx.y;                 // 0..47
    const int which = z >> 4, h = z & 15;
    const float* W = (which == 0 ? Wq : which == 1 ? Wk : Wv) + (size_t)h * C_ * D_;
    const int r0 = blockIdx.x * 64;           // c-dim tile
    const float scale = (which == 0) ? 0.03125f : 1.f;
    ttile64(W + (size_t)r0 * D_, D_, Wt + (size_t)(which * 16 + h) * 64 * C_ + r0, C_, scale);
}

__global__ __launch_bounds__(256) void tw_p(const float* __restrict__ Wp, u16* __restrict__ Wpt) {
    const int r0 = blockIdx.x * 64, c0 = blockIdx.y * 64;
    ttile64(Wp + (size_t)r0 * C_ + c0, C_, Wpt + (size_t)c0 * C_ + r0, C_, 1.f);
}

// ---------------- MFMA GEMM core: 128x128 tile, BK=32, 4 waves, 4x4 frags/wave ----------------
// A [M][K] bf16 row-major, Bt [N][K] bf16 (B transposed). K multiple of 32.
__device__ __forceinline__ void gemm128_core(const u16* __restrict__ A, const u16* __restrict__ Bt,
                                             int m0, int n0, int K,
                                             u16* Asm, u16* Bsm, f32x4 (&acc)[4][4]) {
    const int tid = threadIdx.x;
    const int wid = tid >> 6, lane = tid & 63;
    const int l16 = lane & 15, lq = lane >> 4;
    const int wm = wid >> 1, wn = wid & 1;
    const int srow = lane >> 2;          // 0..15
    const int scol = (lane & 3) * 8;     // element col within BK

    for (int k0 = 0; k0 < K; k0 += 32) {
        __syncthreads();
        #pragma unroll
        for (int it = 0; it < 2; ++it) {
            int row = wid * 32 + it * 16 + srow;
            gload_lds16(A  + (size_t)(m0 + row) * K + k0 + scol, Asm + wid * 1024 + it * 512);
            gload_lds16(Bt + (size_t)(n0 + row) * K + k0 + scol, Bsm + wid * 1024 + it * 512);
        }
        __syncthreads();
        bf16x8 af[4], bfr[4];
        #pragma unroll
        for (int t = 0; t < 4; ++t) {
            af[t]  = *reinterpret_cast<const bf16x8*>(Asm + (wm * 64 + t * 16 + l16) * 32 + lq * 8);
            bfr[t] = *reinterpret_cast<const bf16x8*>(Bsm + (wn * 64 + t * 16 + l16) * 32 + lq * 8);
        }
        #pragma unroll
        for (int mt = 0; mt < 4; ++mt)
            #pragma unroll
            for (int nt = 0; nt < 4; ++nt)
                acc[mt][nt] = __builtin_amdgcn_mfma_f32_16x16x32_bf16(af[mt], bfr[nt], acc[mt][nt], 0, 0, 0);
    }
}

// ---------------- QKV GEMM: [8192 x 1024] @ [1024 x 3072] -> q/k/v bf16 [B,H,T,D] ----------------
__global__ __launch_bounds__(256) void qkv_gemm(const u16* __restrict__ xb, const u16* __restrict__ Wt,
                                                u16* __restrict__ q, u16* __restrict__ k, u16* __restrict__ v) {
    __shared__ u16 Asm[128 * 32], Bsm[128 * 32];
    f32x4 acc[4][4];
    #pragma unroll
    for (int i = 0; i < 4; ++i)
        #pragma unroll
        for (int j = 0; j < 4; ++j) { acc[i][j][0]=0.f; acc[i][j][1]=0.f; acc[i][j][2]=0.f; acc[i][j][3]=0.f; }
    const int m0 = blockIdx.x * 128, n0 = blockIdx.y * 128;
    gemm128_core(xb, Wt, m0, n0, C_, Asm, Bsm, acc);

    const int tid = threadIdx.x, wid = tid >> 6, lane = tid & 63;
    const int l16 = lane & 15, lq = lane >> 4;
    const int wm = wid >> 1, wn = wid & 1;
    #pragma unroll
    for (int mt = 0; mt < 4; ++mt) {
        #pragma unroll
        for (int j = 0; j < 4; ++j) {
            int m = m0 + wm * 64 + mt * 16 + lq * 4 + j;
            int b = m >> 11, t = m & (T_ - 1);
            #pragma unroll
            for (int nt = 0; nt < 4; ++nt) {
                int n = n0 + wn * 64 + nt * 16 + l16;
                int which = n >> 10, h = (n >> 6) & 15, d = n & 63;
                u16* dst = (which == 0 ? q : which == 1 ? k : v);
                dst[((size_t)(b * H_ + h) * T_ + t) * D_ + d] = f2bf(acc[mt][nt][j]);
            }
        }
    }
}

// ---------------- Output GEMM: [8192 x 1024] @ [1024 x 1024] + bias -> fp32 ----------------
__global__ __launch_bounds__(256) void out_gemm(const u16* __restrict__ ob, const u16* __restrict__ Wpt,
                                                const float* __restrict__ bp, float* __restrict__ out) {
    __shared__ u16 Asm[128 * 32], Bsm[128 * 32];
    f32x4 acc[4][4];
    #pragma unroll
    for (int i = 0; i < 4; ++i)
        #pragma unroll
        for (int j = 0; j < 4; ++j) { acc[i][j][0]=0.f; acc[i][j][1]=0.f; acc[i][j][2]=0.f; acc[i][j][3]=0.f; }
    const int m0 = blockIdx.x * 128, n0 = blockIdx.y * 128;
    gemm128_core(ob, Wpt, m0, n0, C_, Asm, Bsm, acc);

    const int tid = threadIdx.x, wid = tid >> 6, lane = tid & 63;
    const int l16 = lane & 15, lq = lane >> 4;
    const int wm = wid >> 1, wn = wid & 1;
    #pragma unroll
    for (int mt = 0; mt < 4; ++mt) {
        #pragma unroll
        for (int j = 0; j < 4; ++j) {
            int m = m0 + wm * 64 + mt * 16 + lq * 4 + j;
            #pragma unroll
            for (int nt = 0; nt < 4; ++nt) {
                int n = n0 + wn * 64 + nt * 16 + l16;
                out[(size_t)m * C_ + n] = acc[mt][nt][j] + bp[n];
            }
        }
    }
}

// ---------------- MFMA flash attention (round-2, o -> bf16) ----------------
__global__ __launch_bounds__(256) void attn_mfma(const u16* __restrict__ q,
                                                 const u16* __restrict__ k,
                                                 const u16* __restrict__ v,
                                                 u16* __restrict__ o) {
    __shared__ u16 Ks[64][72];
    __shared__ u16 Vt[64][72];
    __shared__ u16 Ps[4][16][72];

    const int tid  = threadIdx.x;
    const int wid  = tid >> 6;
    const int lane = tid & 63;
    const int l16  = lane & 15;
    const int lq   = lane >> 4;
    const int q0   = blockIdx.x * 64;
    const int bh   = blockIdx.y;
    const size_t base = (size_t)bh * T_ * D_;

    bf16x8 qa[2];
    {
        const u16* qp = q + base + (size_t)(q0 + wid * 16 + l16) * D_;
        qa[0] = *reinterpret_cast<const bf16x8*>(qp + lq * 8);
        qa[1] = *reinterpret_cast<const bf16x8*>(qp + 32 + lq * 8);
    }

    float mrun[4], lrun[4];
    f32x4 oacc[4];
    #pragma unroll
    for (int j = 0; j < 4; ++j) {
        mrun[j] = -INFINITY; lrun[j] = 0.f;
        oacc[j][0] = 0.f; oacc[j][1] = 0.f; oacc[j][2] = 0.f; oacc[j][3] = 0.f;
    }

    for (int s0 = 0; s0 <= q0; s0 += 64) {
        __syncthreads();
        for (int c = tid; c < 512; c += 256) {
            int row = c >> 3, col8 = (c & 7) * 8;
            ushort8 uk = *reinterpret_cast<const ushort8*>(k + base + (size_t)(s0 + row) * D_ + col8);
            *reinterpret_cast<ushort8*>(&Ks[row][col8]) = uk;
            ushort8 uv = *reinterpret_cast<const ushort8*>(v + base + (size_t)(s0 + row) * D_ + col8);
            #pragma unroll
            for (int i = 0; i < 8; ++i) Vt[col8 + i][row] = uv[i];
        }
        __syncthreads();

        f32x4 sacc[4];
        #pragma unroll
        for (int nt = 0; nt < 4; ++nt) {
            f32x4 a; a[0] = 0.f; a[1] = 0.f; a[2] = 0.f; a[3] = 0.f;
            #pragma unroll
            for (int kc = 0; kc < 2; ++kc) {
                bf16x8 bk = *reinterpret_cast<const bf16x8*>(&Ks[nt * 16 + l16][kc * 32 + lq * 8]);
                a = __builtin_amdgcn_mfma_f32_16x16x32_bf16(qa[kc], bk, a, 0, 0, 0);
            }
            sacc[nt] = a;
        }

        if (s0 == q0) {
            int rowq = wid * 16 + lq * 4;
            #pragma unroll
            for (int nt = 0; nt < 4; ++nt) {
                int col = nt * 16 + l16;
                #pragma unroll
                for (int j = 0; j < 4; ++j)
                    if (col > rowq + j) sacc[nt][j] = -INFINITY;
            }
        }

        float pex[4][4];
        #pragma unroll
        for (int j = 0; j < 4; ++j) {
            float tmax = fmaxf(fmaxf(sacc[0][j], sacc[1][j]), fmaxf(sacc[2][j], sacc[3][j]));
            tmax = fmaxf(tmax, __shfl_xor(tmax, 1));
            tmax = fmaxf(tmax, __shfl_xor(tmax, 2));
            tmax = fmaxf(tmax, __shfl_xor(tmax, 4));
            tmax = fmaxf(tmax, __shfl_xor(tmax, 8));
            float mnew = fmaxf(mrun[j], tmax);
            float scl  = __expf(mrun[j] - mnew);
            float rsum = 0.f;
            #pragma unroll
            for (int nt = 0; nt < 4; ++nt) {
                float p = __expf(sacc[nt][j] - mnew);
                pex[nt][j] = p;
                rsum += p;
            }
            rsum += __shfl_xor(rsum, 1);
            rsum += __shfl_xor(rsum, 2);
            rsum += __shfl_xor(rsum, 4);
            rsum += __shfl_xor(rsum, 8);
            lrun[j] = lrun[j] * scl + rsum;
            mrun[j] = mnew;
            #pragma unroll
            for (int dt = 0; dt < 4; ++dt) oacc[dt][j] *= scl;
        }

        #pragma unroll
        for (int nt = 0; nt < 4; ++nt)
            #pragma unroll
            for (int j = 0; j < 4; ++j)
                Ps[wid][lq * 4 + j][nt * 16 + l16] = f2bf(pex[nt][j]);

        #pragma unroll
        for (int dt = 0; dt < 4; ++dt) {
            #pragma unroll
            for (int kc = 0; kc < 2; ++kc) {
                bf16x8 pa = *reinterpret_cast<const bf16x8*>(&Ps[wid][l16][kc * 32 + lq * 8]);
                bf16x8 vb = *reinterpret_cast<const bf16x8*>(&Vt[dt * 16 + l16][kc * 32 + lq * 8]);
                oacc[dt] = __builtin_amdgcn_mfma_f32_16x16x32_bf16(pa, vb, oacc[dt], 0, 0, 0);
            }
        }
    }

    const int b = bh / H_, h = bh % H_;
    const int qrow = q0 + wid * 16 + lq * 4;
    #pragma unroll
    for (int j = 0; j < 4; ++j) {
        float inv = 1.f / lrun[j];
        size_t obi = ((size_t)b * T_ + qrow + j) * C_ + h * D_ + l16;
        #pragma unroll
        for (int dt = 0; dt < 4; ++dt)
            o[obi + dt * 16] = f2bf(oacc[dt][j] * inv);
    }
}

extern "C" void kernel_launch(void* const* d_in, const int* in_sizes, int n_in,
                              void* d_out, int out_size, void* d_ws, size_t ws_size,
                              hipStream_t stream) {
    const float* x  = (const float*)d_in[0];
    const float* Wq = (const float*)d_in[1];
    const float* Wk = (const float*)d_in[2];
    const float* Wv = (const float*)d_in[3];
    const float* Wp = (const float*)d_in[4];
    const float* bp = (const float*)d_in[5];
    float* out = (float*)d_out;

    const size_t E = (size_t)M_ * C_;        // 8.39M elems
    u16* xb  = (u16*)d_ws;
    u16* qb  = xb  + E;
    u16* kb  = qb  + E;
    u16* vb  = kb  + E;
    u16* obf = vb  + E;
    u16* Wt  = obf + E;                      // [3072][1024]
    u16* Wpt = Wt  + (size_t)3072 * 1024;    // [1024][1024]

    cast_x<<<(E / 2048), 256, 0, stream>>>(x, xb);
    tw_qkv<<<dim3(16, 48), 256, 0, stream>>>(Wq, Wk, Wv, Wt);
    tw_p<<<dim3(16, 16), 256, 0, stream>>>(Wp, Wpt);

    qkv_gemm<<<dim3(M_ / 128, 3072 / 128), 256, 0, stream>>>(xb, Wt, qb, kb, vb);

    attn_mfma<<<dim3(T_ / 64, B_ * H_), 256, 0, stream>>>(qb, kb, vb, obf);

    out_gemm<<<dim3(M_ / 128, C_ / 128), 256, 0, stream>>>(obf, Wpt, bp, out);
}

// Round 4
// 235.491 us; speedup vs baseline: 9.1477x; 1.7213x over previous
//
#include <hip/hip_runtime.h>
#include <hip/hip_bf16.h>

// B=4, T=2048, C=1024, H=16, D=64. fp32 in/out.
// cast_x / transpose weights -> qkv_gemm (MFMA) -> tv (V->V^T) -> attn (MFMA flash,
// swapped-QK^T, swizzled gload_lds staging, 2-phase pipeline) -> out_gemm (MFMA+bias).

#define B_ 4
#define T_ 2048
#define C_ 1024
#define H_ 16
#define D_ 64
#define M_ (B_*T_)      // 8192

typedef unsigned short u16;
typedef unsigned short ushort8 __attribute__((ext_vector_type(8)));
typedef __attribute__((ext_vector_type(8))) short bf16x8;
typedef __attribute__((ext_vector_type(4))) float f32x4;

__device__ __forceinline__ u16 f2bf(float f) {
    __hip_bfloat16 h = __float2bfloat16(f);
    return *reinterpret_cast<u16*>(&h);
}

__device__ __forceinline__ void gload_lds16(const void* g, void* lds) {
    __builtin_amdgcn_global_load_lds((const __attribute__((address_space(1))) unsigned int*)g,
                                     (__attribute__((address_space(3))) unsigned int*)lds, 16, 0, 0);
}

// ---------------- cast x -> bf16 ----------------
__global__ __launch_bounds__(256) void cast_x(const float* __restrict__ in, u16* __restrict__ out) {
    int i = (blockIdx.x * 256 + threadIdx.x) * 8;
    float4 a = *reinterpret_cast<const float4*>(in + i);
    float4 b = *reinterpret_cast<const float4*>(in + i + 4);
    ushort8 o;
    o[0]=f2bf(a.x); o[1]=f2bf(a.y); o[2]=f2bf(a.z); o[3]=f2bf(a.w);
    o[4]=f2bf(b.x); o[5]=f2bf(b.y); o[6]=f2bf(b.z); o[7]=f2bf(b.w);
    *reinterpret_cast<ushort8*>(out + i) = o;
}

// ---------------- 64x64 transpose+cast: out[c][r] = in[r][c]*scale ----------------
__device__ __forceinline__ void ttile64(const float* __restrict__ in, int ldin,
                                        u16* __restrict__ out, int ldout, float scale) {
    __shared__ float t[64][65];
    const int tid = threadIdx.x;
    {
        int c = tid & 63, rr = tid >> 6;
        #pragma unroll
        for (int i = 0; i < 16; ++i) {
            int r = i * 4 + rr;
            t[r][c] = in[(size_t)r * ldin + c];
        }
    }
    __syncthreads();
    {
        int r2 = tid & 63, cg = tid >> 6;
        #pragma unroll
        for (int i = 0; i < 16; ++i) {
            int cc = i * 4 + cg;
            out[(size_t)cc * ldout + r2] = f2bf(t[r2][cc] * scale);
        }
    }
}

__global__ __launch_bounds__(256) void tw_qkv(const float* __restrict__ Wq, const float* __restrict__ Wk,
                                              const float* __restrict__ Wv, u16* __restrict__ Wt) {
    const int z = blockIdx.y;                 // 0..47
    const int which = z >> 4, h = z & 15;
    const float* W = (which == 0 ? Wq : which == 1 ? Wk : Wv) + (size_t)h * C_ * D_;
    const int r0 = blockIdx.x * 64;
    const float scale = (which == 0) ? 0.03125f : 1.f;    // fold C^-0.5 into Wq
    ttile64(W + (size_t)r0 * D_, D_, Wt + (size_t)(which * 16 + h) * 64 * C_ + r0, C_, scale);
}

__global__ __launch_bounds__(256) void tw_p(const float* __restrict__ Wp, u16* __restrict__ Wpt) {
    const int r0 = blockIdx.x * 64, c0 = blockIdx.y * 64;
    ttile64(Wp + (size_t)r0 * C_ + c0, C_, Wpt + (size_t)c0 * C_ + r0, C_, 1.f);
}

// ---------------- V [b,h,t,d] -> V^T [b,h,d,t] (bf16) ----------------
__global__ __launch_bounds__(256) void tv(const u16* __restrict__ v, u16* __restrict__ vT) {
    __shared__ u16 t[64][72];
    const int tid = threadIdx.x;
    const int t0 = blockIdx.x * 64, bh = blockIdx.y;
    const u16* src = v + ((size_t)bh * T_ + t0) * D_;
    #pragma unroll
    for (int it = 0; it < 2; ++it) {
        int idx = it * 256 + tid;
        int r = idx >> 3, c8 = (idx & 7) * 8;
        *reinterpret_cast<ushort8*>(&t[r][c8]) =
            *reinterpret_cast<const ushort8*>(src + (size_t)r * D_ + c8);
    }
    __syncthreads();
    #pragma unroll
    for (int it = 0; it < 2; ++it) {
        int idx = it * 256 + tid;
        int d = idx >> 3, c8 = (idx & 7) * 8;
        ushort8 w;
        #pragma unroll
        for (int i = 0; i < 8; ++i) w[i] = t[c8 + i][d];
        *reinterpret_cast<ushort8*>(vT + ((size_t)bh * D_ + d) * T_ + t0 + c8) = w;
    }
}

// ---------------- MFMA GEMM core: 128x128 tile, BK=32, 4 waves, 4x4 frags/wave ----------------
__device__ __forceinline__ void gemm128_core(const u16* __restrict__ A, const u16* __restrict__ Bt,
                                             int m0, int n0, int K,
                                             u16* Asm, u16* Bsm, f32x4 (&acc)[4][4]) {
    const int tid = threadIdx.x;
    const int wid = tid >> 6, lane = tid & 63;
    const int l16 = lane & 15, lq = lane >> 4;
    const int wm = wid >> 1, wn = wid & 1;
    const int srow = lane >> 2;
    const int scol = (lane & 3) * 8;

    for (int k0 = 0; k0 < K; k0 += 32) {
        __syncthreads();
        #pragma unroll
        for (int it = 0; it < 2; ++it) {
            int row = wid * 32 + it * 16 + srow;
            gload_lds16(A  + (size_t)(m0 + row) * K + k0 + scol, Asm + wid * 1024 + it * 512);
            gload_lds16(Bt + (size_t)(n0 + row) * K + k0 + scol, Bsm + wid * 1024 + it * 512);
        }
        __syncthreads();
        bf16x8 af[4], bfr[4];
        #pragma unroll
        for (int t = 0; t < 4; ++t) {
            af[t]  = *reinterpret_cast<const bf16x8*>(Asm + (wm * 64 + t * 16 + l16) * 32 + lq * 8);
            bfr[t] = *reinterpret_cast<const bf16x8*>(Bsm + (wn * 64 + t * 16 + l16) * 32 + lq * 8);
        }
        #pragma unroll
        for (int mt = 0; mt < 4; ++mt)
            #pragma unroll
            for (int nt = 0; nt < 4; ++nt)
                acc[mt][nt] = __builtin_amdgcn_mfma_f32_16x16x32_bf16(af[mt], bfr[nt], acc[mt][nt], 0, 0, 0);
    }
}

// ---------------- QKV GEMM ----------------
__global__ __launch_bounds__(256) void qkv_gemm(const u16* __restrict__ xb, const u16* __restrict__ Wt,
                                                u16* __restrict__ q, u16* __restrict__ k, u16* __restrict__ v) {
    __shared__ u16 Asm[128 * 32], Bsm[128 * 32];
    f32x4 acc[4][4];
    #pragma unroll
    for (int i = 0; i < 4; ++i)
        #pragma unroll
        for (int j = 0; j < 4; ++j) { acc[i][j][0]=0.f; acc[i][j][1]=0.f; acc[i][j][2]=0.f; acc[i][j][3]=0.f; }
    const int m0 = blockIdx.x * 128, n0 = blockIdx.y * 128;
    gemm128_core(xb, Wt, m0, n0, C_, Asm, Bsm, acc);

    const int tid = threadIdx.x, wid = tid >> 6, lane = tid & 63;
    const int l16 = lane & 15, lq = lane >> 4;
    const int wm = wid >> 1, wn = wid & 1;
    #pragma unroll
    for (int mt = 0; mt < 4; ++mt) {
        #pragma unroll
        for (int j = 0; j < 4; ++j) {
            int m = m0 + wm * 64 + mt * 16 + lq * 4 + j;
            int b = m >> 11, t = m & (T_ - 1);
            #pragma unroll
            for (int nt = 0; nt < 4; ++nt) {
                int n = n0 + wn * 64 + nt * 16 + l16;
                int which = n >> 10, h = (n >> 6) & 15, d = n & 63;
                u16* dst = (which == 0 ? q : which == 1 ? k : v);
                dst[((size_t)(b * H_ + h) * T_ + t) * D_ + d] = f2bf(acc[mt][nt][j]);
            }
        }
    }
}

// ---------------- Output GEMM ----------------
__global__ __launch_bounds__(256) void out_gemm(const u16* __restrict__ ob, const u16* __restrict__ Wpt,
                                                const float* __restrict__ bp, float* __restrict__ out) {
    __shared__ u16 Asm[128 * 32], Bsm[128 * 32];
    f32x4 acc[4][4];
    #pragma unroll
    for (int i = 0; i < 4; ++i)
        #pragma unroll
        for (int j = 0; j < 4; ++j) { acc[i][j][0]=0.f; acc[i][j][1]=0.f; acc[i][j][2]=0.f; acc[i][j][3]=0.f; }
    const int m0 = blockIdx.x * 128, n0 = blockIdx.y * 128;
    gemm128_core(ob, Wpt, m0, n0, C_, Asm, Bsm, acc);

    const int tid = threadIdx.x, wid = tid >> 6, lane = tid & 63;
    const int l16 = lane & 15, lq = lane >> 4;
    const int wm = wid >> 1, wn = wid & 1;
    #pragma unroll
    for (int mt = 0; mt < 4; ++mt) {
        #pragma unroll
        for (int j = 0; j < 4; ++j) {
            int m = m0 + wm * 64 + mt * 16 + lq * 4 + j;
            #pragma unroll
            for (int nt = 0; nt < 4; ++nt) {
                int n = n0 + wn * 64 + nt * 16 + l16;
                out[(size_t)m * C_ + n] = acc[mt][nt][j] + bp[n];
            }
        }
    }
}

// ---------------- MFMA flash attention v2 ----------------
// 4 waves x 16 q-rows. Swapped QK^T: S^T = mfma(A=K, B=Q) -> lane (l16=q-col, lq) holds
// S[q][s], s = nt*16+lq*4+j. s-reduce = 15 local + 2 shfl. K/V^T staged via global_load_lds
// with XOR-swizzled source granules (c^(r&7)); frag reads apply same swizzle. 2-phase dbuf.
__global__ __launch_bounds__(256, 4) void attn_mfma(const u16* __restrict__ q,
                                                    const u16* __restrict__ k,
                                                    const u16* __restrict__ vT,
                                                    u16* __restrict__ o) {
    __shared__ u16 Ks[2][64 * 64];   // row s, 128B rows, swizzled granules
    __shared__ u16 Vs[2][64 * 64];   // row d, cols s
    __shared__ u16 Ps[4][16 * 64];   // per-wave P[q][s], swizzled

    const int tid  = threadIdx.x;
    const int wid  = tid >> 6;
    const int lane = tid & 63;
    const int l16  = lane & 15;
    const int lq   = lane >> 4;
    const int q0   = (31 - blockIdx.x) * 64;       // big tiles first (tail fix)
    const int bh   = blockIdx.y;
    const size_t base = (size_t)bh * T_ * D_;
    const u16* kp  = k  + base;
    const u16* vtp = vT + (size_t)bh * D_ * T_;

    // Q B-frag (col = l16 -> q-row q0+wid*16+l16, k = kc*32+lq*8+i)
    bf16x8 qb[2];
    {
        const u16* qp = q + base + (size_t)(q0 + wid * 16 + l16) * D_;
        qb[0] = *reinterpret_cast<const bf16x8*>(qp + lq * 8);
        qb[1] = *reinterpret_cast<const bf16x8*>(qp + 32 + lq * 8);
    }

    float mrun = -INFINITY, lrun = 0.f;            // indexed by q = l16 (dup over lq)
    f32x4 oacc[4];                                 // [dt]: col=l16=d, row j -> q=lq*4+j
    #pragma unroll
    for (int dt = 0; dt < 4; ++dt) { oacc[dt][0]=0.f; oacc[dt][1]=0.f; oacc[dt][2]=0.f; oacc[dt][3]=0.f; }

    const int ntile = q0 / 64 + 1;
    const int qglob = q0 + wid * 16 + l16;

#define STAGE(buf, s0b)                                                              \
    {                                                                                \
        _Pragma("unroll")                                                            \
        for (int it = 0; it < 2; ++it) {                                             \
            int g = it * 256 + wid * 64 + lane;                                      \
            int r = g >> 3, cg = (g & 7) ^ (r & 7);                                  \
            gload_lds16(kp + (size_t)(s0b + r) * D_ + cg * 8,                        \
                        &Ks[buf][(it * 256 + wid * 64) * 8]);                        \
            gload_lds16(vtp + (size_t)r * T_ + (s0b) + cg * 8,                       \
                        &Vs[buf][(it * 256 + wid * 64) * 8]);                        \
        }                                                                            \
    }

    STAGE(0, 0);
    __syncthreads();

    for (int t = 0; t < ntile; ++t) {
        const int cur = t & 1;
        if (t + 1 < ntile) STAGE(cur ^ 1, (t + 1) * 64);

        // swizzled granule offsets (shared by K/V/P fragment reads)
        // ---- S^T = K . Q ----
        f32x4 st[4];
        #pragma unroll
        for (int nt = 0; nt < 4; ++nt) { st[nt][0]=0.f; st[nt][1]=0.f; st[nt][2]=0.f; st[nt][3]=0.f; }
        #pragma unroll
        for (int kc = 0; kc < 2; ++kc) {
            const int cswz = ((kc * 4 + lq) ^ (l16 & 7)) * 16;
            #pragma unroll
            for (int nt = 0; nt < 4; ++nt) {
                bf16x8 ka = *reinterpret_cast<const bf16x8*>(
                    reinterpret_cast<const char*>(&Ks[cur][0]) + (nt * 16 + l16) * 128 + cswz);
                st[nt] = __builtin_amdgcn_mfma_f32_16x16x32_bf16(ka, qb[kc], st[nt], 0, 0, 0);
            }
        }

        // ---- causal mask (diagonal tile only): s = t*64 + nt*16 + lq*4 + j ----
        if (t == ntile - 1) {
            #pragma unroll
            for (int nt = 0; nt < 4; ++nt) {
                int sb = q0 + nt * 16 + lq * 4;
                #pragma unroll
                for (int j = 0; j < 4; ++j)
                    if (sb + j > qglob) st[nt][j] = -INFINITY;
            }
        }

        // ---- online softmax over s (16 regs + lanes l16+16*lq) ----
        float tmax = -INFINITY;
        #pragma unroll
        for (int nt = 0; nt < 4; ++nt)
            #pragma unroll
            for (int j = 0; j < 4; ++j) tmax = fmaxf(tmax, st[nt][j]);
        tmax = fmaxf(tmax, __shfl_xor(tmax, 16));
        tmax = fmaxf(tmax, __shfl_xor(tmax, 32));
        float mnew = fmaxf(mrun, tmax);
        float scl  = __expf(mrun - mnew);
        float rsum = 0.f;
        #pragma unroll
        for (int nt = 0; nt < 4; ++nt)
            #pragma unroll
            for (int j = 0; j < 4; ++j) {
                float p = __expf(st[nt][j] - mnew);
                st[nt][j] = p;
                rsum += p;
            }
        rsum += __shfl_xor(rsum, 16);
        rsum += __shfl_xor(rsum, 32);
        lrun = lrun * scl + rsum;
        mrun = mnew;
        #pragma unroll
        for (int j = 0; j < 4; ++j) {
            float sj = __shfl(scl, lq * 4 + j);    // scl for q-row lq*4+j
            #pragma unroll
            for (int dt = 0; dt < 4; ++dt) oacc[dt][j] *= sj;
        }

        // ---- P[q=l16][s=nt*16+lq*4+..] -> swizzled LDS (b64 packed) ----
        #pragma unroll
        for (int nt = 0; nt < 4; ++nt) {
            unsigned lo = (unsigned)f2bf(st[nt][0]) | ((unsigned)f2bf(st[nt][1]) << 16);
            unsigned hi = (unsigned)f2bf(st[nt][2]) | ((unsigned)f2bf(st[nt][3]) << 16);
            int byteoff = (l16 * 128 + nt * 32 + lq * 8) ^ ((l16 & 7) << 4);
            *reinterpret_cast<uint2*>(reinterpret_cast<char*>(&Ps[wid][0]) + byteoff) =
                make_uint2(lo, hi);
        }

        // ---- O += P . V ----
        #pragma unroll
        for (int kc = 0; kc < 2; ++kc) {
            const int cswz = ((kc * 4 + lq) ^ (l16 & 7)) * 16;
            bf16x8 pa = *reinterpret_cast<const bf16x8*>(
                reinterpret_cast<const char*>(&Ps[wid][0]) + l16 * 128 + cswz);
            #pragma unroll
            for (int dt = 0; dt < 4; ++dt) {
                bf16x8 vb = *reinterpret_cast<const bf16x8*>(
                    reinterpret_cast<const char*>(&Vs[cur][0]) + (dt * 16 + l16) * 128 + cswz);
                oacc[dt] = __builtin_amdgcn_mfma_f32_16x16x32_bf16(pa, vb, oacc[dt], 0, 0, 0);
            }
        }
        __syncthreads();
    }
#undef STAGE

    // ---- epilogue ----
    const int b = bh / H_, h = bh % H_;
    float linv = 1.f / lrun;
    #pragma unroll
    for (int j = 0; j < 4; ++j) {
        float lj = __shfl(linv, lq * 4 + j);
        size_t obi = ((size_t)b * T_ + q0 + wid * 16 + lq * 4 + j) * C_ + h * D_ + l16;
        #pragma unroll
        for (int dt = 0; dt < 4; ++dt)
            o[obi + dt * 16] = f2bf(oacc[dt][j] * lj);
    }
}

extern "C" void kernel_launch(void* const* d_in, const int* in_sizes, int n_in,
                              void* d_out, int out_size, void* d_ws, size_t ws_size,
                              hipStream_t stream) {
    const float* x  = (const float*)d_in[0];
    const float* Wq = (const float*)d_in[1];
    const float* Wk = (const float*)d_in[2];
    const float* Wv = (const float*)d_in[3];
    const float* Wp = (const float*)d_in[4];
    const float* bp = (const float*)d_in[5];
    float* out = (float*)d_out;

    const size_t E = (size_t)M_ * C_;
    u16* xb  = (u16*)d_ws;                   // also reused as vT after qkv_gemm
    u16* qb  = xb  + E;
    u16* kb  = qb  + E;
    u16* vb  = kb  + E;
    u16* obf = vb  + E;
    u16* Wt  = obf + E;                      // [3072][1024]
    u16* Wpt = Wt  + (size_t)3072 * 1024;    // [1024][1024]
    u16* vTb = xb;                           // alias: xb dead after qkv_gemm

    cast_x<<<(E / 2048), 256, 0, stream>>>(x, xb);
    tw_qkv<<<dim3(16, 48), 256, 0, stream>>>(Wq, Wk, Wv, Wt);
    tw_p<<<dim3(16, 16), 256, 0, stream>>>(Wp, Wpt);

    qkv_gemm<<<dim3(M_ / 128, 3072 / 128), 256, 0, stream>>>(xb, Wt, qb, kb, vb);

    tv<<<dim3(T_ / 64, B_ * H_), 256, 0, stream>>>(vb, vTb);

    attn_mfma<<<dim3(T_ / 64, B_ * H_), 256, 0, stream>>>(qb, kb, vTb, obf);

    out_gemm<<<dim3(M_ / 128, C_ / 128), 256, 0, stream>>>(obf, Wpt, bp, out);
}

// Round 5
// 232.941 us; speedup vs baseline: 9.2479x; 1.0109x over previous
//
#include <hip/hip_runtime.h>
#include <hip/hip_bf16.h>

// B=4, T=2048, C=1024, H=16, D=64. fp32 in/out.
// cast_x / transpose weights -> qkv_gemm (MFMA 128x128) -> tv (V->V^T) ->
// attn (MFMA 32x32x16 flash, swapped QK^T, O^T form, in-register P exchange) -> out_gemm.

#define B_ 4
#define T_ 2048
#define C_ 1024
#define H_ 16
#define D_ 64
#define M_ (B_*T_)      // 8192

typedef unsigned short u16;
typedef unsigned short ushort8 __attribute__((ext_vector_type(8)));
typedef unsigned int uint4v __attribute__((ext_vector_type(4)));
typedef __attribute__((ext_vector_type(8))) short bf16x8;
typedef __attribute__((ext_vector_type(4))) float f32x4;
typedef __attribute__((ext_vector_type(16))) float f32x16;

__device__ __forceinline__ u16 f2bf(float f) {
    __hip_bfloat16 h = __float2bfloat16(f);
    return *reinterpret_cast<u16*>(&h);
}
__device__ __forceinline__ unsigned pk2(float a, float b) {
    return (unsigned)f2bf(a) | ((unsigned)f2bf(b) << 16);
}

__device__ __forceinline__ void gload_lds16(const void* g, void* lds) {
    __builtin_amdgcn_global_load_lds((const __attribute__((address_space(1))) unsigned int*)g,
                                     (__attribute__((address_space(3))) unsigned int*)lds, 16, 0, 0);
}

// ---------------- cast x -> bf16 ----------------
__global__ __launch_bounds__(256) void cast_x(const float* __restrict__ in, u16* __restrict__ out) {
    int i = (blockIdx.x * 256 + threadIdx.x) * 8;
    float4 a = *reinterpret_cast<const float4*>(in + i);
    float4 b = *reinterpret_cast<const float4*>(in + i + 4);
    ushort8 o;
    o[0]=f2bf(a.x); o[1]=f2bf(a.y); o[2]=f2bf(a.z); o[3]=f2bf(a.w);
    o[4]=f2bf(b.x); o[5]=f2bf(b.y); o[6]=f2bf(b.z); o[7]=f2bf(b.w);
    *reinterpret_cast<ushort8*>(out + i) = o;
}

// ---------------- 64x64 transpose+cast: out[c][r] = in[r][c]*scale ----------------
__device__ __forceinline__ void ttile64(const float* __restrict__ in, int ldin,
                                        u16* __restrict__ out, int ldout, float scale) {
    __shared__ float t[64][65];
    const int tid = threadIdx.x;
    {
        int c = tid & 63, rr = tid >> 6;
        #pragma unroll
        for (int i = 0; i < 16; ++i) {
            int r = i * 4 + rr;
            t[r][c] = in[(size_t)r * ldin + c];
        }
    }
    __syncthreads();
    {
        int r2 = tid & 63, cg = tid >> 6;
        #pragma unroll
        for (int i = 0; i < 16; ++i) {
            int cc = i * 4 + cg;
            out[(size_t)cc * ldout + r2] = f2bf(t[r2][cc] * scale);
        }
    }
}

__global__ __launch_bounds__(256) void tw_qkv(const float* __restrict__ Wq, const float* __restrict__ Wk,
                                              const float* __restrict__ Wv, u16* __restrict__ Wt) {
    const int z = blockIdx.y;
    const int which = z >> 4, h = z & 15;
    const float* W = (which == 0 ? Wq : which == 1 ? Wk : Wv) + (size_t)h * C_ * D_;
    const int r0 = blockIdx.x * 64;
    const float scale = (which == 0) ? 0.03125f : 1.f;    // fold C^-0.5 into Wq
    ttile64(W + (size_t)r0 * D_, D_, Wt + (size_t)(which * 16 + h) * 64 * C_ + r0, C_, scale);
}

__global__ __launch_bounds__(256) void tw_p(const float* __restrict__ Wp, u16* __restrict__ Wpt) {
    const int r0 = blockIdx.x * 64, c0 = blockIdx.y * 64;
    ttile64(Wp + (size_t)r0 * C_ + c0, C_, Wpt + (size_t)c0 * C_ + r0, C_, 1.f);
}

// ---------------- V [b,h,t,d] -> V^T [b,h,d,t] (bf16) ----------------
__global__ __launch_bounds__(256) void tv(const u16* __restrict__ v, u16* __restrict__ vT) {
    __shared__ u16 t[64][72];
    const int tid = threadIdx.x;
    const int t0 = blockIdx.x * 64, bh = blockIdx.y;
    const u16* src = v + ((size_t)bh * T_ + t0) * D_;
    #pragma unroll
    for (int it = 0; it < 2; ++it) {
        int idx = it * 256 + tid;
        int r = idx >> 3, c8 = (idx & 7) * 8;
        *reinterpret_cast<ushort8*>(&t[r][c8]) =
            *reinterpret_cast<const ushort8*>(src + (size_t)r * D_ + c8);
    }
    __syncthreads();
    #pragma unroll
    for (int it = 0; it < 2; ++it) {
        int idx = it * 256 + tid;
        int d = idx >> 3, c8 = (idx & 7) * 8;
        ushort8 w;
        #pragma unroll
        for (int i = 0; i < 8; ++i) w[i] = t[c8 + i][d];
        *reinterpret_cast<ushort8*>(vT + ((size_t)bh * D_ + d) * T_ + t0 + c8) = w;
    }
}

// ---------------- MFMA GEMM core: 128x128 tile, BK=32, 4 waves, 4x4 frags/wave ----------------
__device__ __forceinline__ void gemm128_core(const u16* __restrict__ A, const u16* __restrict__ Bt,
                                             int m0, int n0, int K,
                                             u16* Asm, u16* Bsm, f32x4 (&acc)[4][4]) {
    const int tid = threadIdx.x;
    const int wid = tid >> 6, lane = tid & 63;
    const int l16 = lane & 15, lq = lane >> 4;
    const int wm = wid >> 1, wn = wid & 1;
    const int srow = lane >> 2;
    const int scol = (lane & 3) * 8;

    for (int k0 = 0; k0 < K; k0 += 32) {
        __syncthreads();
        #pragma unroll
        for (int it = 0; it < 2; ++it) {
            int row = wid * 32 + it * 16 + srow;
            gload_lds16(A  + (size_t)(m0 + row) * K + k0 + scol, Asm + wid * 1024 + it * 512);
            gload_lds16(Bt + (size_t)(n0 + row) * K + k0 + scol, Bsm + wid * 1024 + it * 512);
        }
        __syncthreads();
        bf16x8 af[4], bfr[4];
        #pragma unroll
        for (int t = 0; t < 4; ++t) {
            af[t]  = *reinterpret_cast<const bf16x8*>(Asm + (wm * 64 + t * 16 + l16) * 32 + lq * 8);
            bfr[t] = *reinterpret_cast<const bf16x8*>(Bsm + (wn * 64 + t * 16 + l16) * 32 + lq * 8);
        }
        #pragma unroll
        for (int mt = 0; mt < 4; ++mt)
            #pragma unroll
            for (int nt = 0; nt < 4; ++nt)
                acc[mt][nt] = __builtin_amdgcn_mfma_f32_16x16x32_bf16(af[mt], bfr[nt], acc[mt][nt], 0, 0, 0);
    }
}

// ---------------- QKV GEMM ----------------
__global__ __launch_bounds__(256) void qkv_gemm(const u16* __restrict__ xb, const u16* __restrict__ Wt,
                                                u16* __restrict__ q, u16* __restrict__ k, u16* __restrict__ v) {
    __shared__ u16 Asm[128 * 32], Bsm[128 * 32];
    f32x4 acc[4][4];
    #pragma unroll
    for (int i = 0; i < 4; ++i)
        #pragma unroll
        for (int j = 0; j < 4; ++j) { acc[i][j][0]=0.f; acc[i][j][1]=0.f; acc[i][j][2]=0.f; acc[i][j][3]=0.f; }
    const int m0 = blockIdx.x * 128, n0 = blockIdx.y * 128;
    gemm128_core(xb, Wt, m0, n0, C_, Asm, Bsm, acc);

    const int tid = threadIdx.x, wid = tid >> 6, lane = tid & 63;
    const int l16 = lane & 15, lq = lane >> 4;
    const int wm = wid >> 1, wn = wid & 1;
    #pragma unroll
    for (int mt = 0; mt < 4; ++mt) {
        #pragma unroll
        for (int j = 0; j < 4; ++j) {
            int m = m0 + wm * 64 + mt * 16 + lq * 4 + j;
            int b = m >> 11, t = m & (T_ - 1);
            #pragma unroll
            for (int nt = 0; nt < 4; ++nt) {
                int n = n0 + wn * 64 + nt * 16 + l16;
                int which = n >> 10, h = (n >> 6) & 15, d = n & 63;
                u16* dst = (which == 0 ? q : which == 1 ? k : v);
                dst[((size_t)(b * H_ + h) * T_ + t) * D_ + d] = f2bf(acc[mt][nt][j]);
            }
        }
    }
}

// ---------------- Output GEMM ----------------
__global__ __launch_bounds__(256) void out_gemm(const u16* __restrict__ ob, const u16* __restrict__ Wpt,
                                                const float* __restrict__ bp, float* __restrict__ out) {
    __shared__ u16 Asm[128 * 32], Bsm[128 * 32];
    f32x4 acc[4][4];
    #pragma unroll
    for (int i = 0; i < 4; ++i)
        #pragma unroll
        for (int j = 0; j < 4; ++j) { acc[i][j][0]=0.f; acc[i][j][1]=0.f; acc[i][j][2]=0.f; acc[i][j][3]=0.f; }
    const int m0 = blockIdx.x * 128, n0 = blockIdx.y * 128;
    gemm128_core(ob, Wpt, m0, n0, C_, Asm, Bsm, acc);

    const int tid = threadIdx.x, wid = tid >> 6, lane = tid & 63;
    const int l16 = lane & 15, lq = lane >> 4;
    const int wm = wid >> 1, wn = wid & 1;
    #pragma unroll
    for (int mt = 0; mt < 4; ++mt) {
        #pragma unroll
        for (int j = 0; j < 4; ++j) {
            int m = m0 + wm * 64 + mt * 16 + lq * 4 + j;
            #pragma unroll
            for (int nt = 0; nt < 4; ++nt) {
                int n = n0 + wn * 64 + nt * 16 + l16;
                out[(size_t)m * C_ + n] = acc[mt][nt][j] + bp[n];
            }
        }
    }
}

// ---------------- MFMA flash attention v3: 32x32x16, QBLK=128, O^T form ----------------
// 4 waves x 32 q-rows. S^T = mfma(A=K, B=Q): C/D col=lane&31=q, row=(reg&3)+8*(reg>>2)+4*(lane>>5)=s.
// Softmax fully lane-local (+1 shfl_xor(32)). P -> PV B-frag via packed shfl_xor(32) exchange.
// O^T = mfma(A=V^T, B=P^T); epilogue transposes via LDS. K/V^T staged swizzled via global_load_lds.
__global__ __launch_bounds__(256) void attn_mfma(const u16* __restrict__ q,
                                                 const u16* __restrict__ k,
                                                 const u16* __restrict__ vT,
                                                 u16* __restrict__ o) {
    __shared__ u16 smem[2][2][4096];   // [K|V][dbuf][64x64 tile], 32 KiB

    const int tid  = threadIdx.x;
    const int wid  = tid >> 6;
    const int lane = tid & 63;
    const int l31  = lane & 31;
    const int hi   = lane >> 5;
    const int qb   = 15 - blockIdx.x;              // big tiles first
    const int q0   = qb * 128;
    const int bh   = blockIdx.y;
    const size_t base = (size_t)bh * T_ * D_;
    const u16* kp  = k  + base;
    const u16* vtp = vT + (size_t)bh * D_ * T_;
    const int qglob = q0 + wid * 32 + l31;

    // Q B-frags: col=l31=q, k = kc*16 + hi*8 + i
    bf16x8 qf[4];
    {
        const u16* qp = q + base + (size_t)qglob * D_;
        #pragma unroll
        for (int kc = 0; kc < 4; ++kc)
            qf[kc] = *reinterpret_cast<const bf16x8*>(qp + kc * 16 + hi * 8);
    }

    float mrun = -INFINITY, lrun = 0.f;
    f32x16 oacc[2];                                 // O^T: col=q(=l31), row d = mt*32+(r&3)+8*(r>>2)+4*hi
    #pragma unroll
    for (int mt = 0; mt < 2; ++mt)
        #pragma unroll
        for (int r = 0; r < 16; ++r) oacc[mt][r] = 0.f;

    const int ntile  = 2 * qb + 2;
    const int diag_t = 2 * qb + (wid >> 1);

#define STAGE(buf, s0b)                                                              \
    {                                                                                \
        _Pragma("unroll")                                                            \
        for (int it = 0; it < 2; ++it) {                                             \
            int g = it * 256 + wid * 64 + lane;                                      \
            int r = g >> 3, cg = (g & 7) ^ (r & 7);                                  \
            gload_lds16(kp + (size_t)(s0b + r) * D_ + cg * 8,                        \
                        &smem[0][buf][(it * 256 + wid * 64) * 8]);                   \
            gload_lds16(vtp + (size_t)r * T_ + (s0b) + cg * 8,                       \
                        &smem[1][buf][(it * 256 + wid * 64) * 8]);                   \
        }                                                                            \
    }

    STAGE(0, 0);
    __syncthreads();

    for (int t = 0; t < ntile; ++t) {
        const int cur = t & 1;
        if (t + 1 < ntile) STAGE(cur ^ 1, (t + 1) * 64);

        if (t <= diag_t) {                          // wave-uniform skip of fully-masked tiles
            const char* Kb = reinterpret_cast<const char*>(&smem[0][cur][0]);
            const char* Vb = reinterpret_cast<const char*>(&smem[1][cur][0]);

            // ---- S^T = K . Q ----
            f32x16 st[2];
            #pragma unroll
            for (int mt = 0; mt < 2; ++mt)
                #pragma unroll
                for (int r = 0; r < 16; ++r) st[mt][r] = 0.f;
            __builtin_amdgcn_s_setprio(1);
            #pragma unroll
            for (int kc = 0; kc < 4; ++kc) {
                #pragma unroll
                for (int mt = 0; mt < 2; ++mt) {
                    int row = mt * 32 + l31;
                    bf16x8 ka = *reinterpret_cast<const bf16x8*>(
                        Kb + row * 128 + (((kc * 2 + hi) ^ (l31 & 7)) << 4));
                    st[mt] = __builtin_amdgcn_mfma_f32_32x32x16_bf16(ka, qf[kc], st[mt], 0, 0, 0);
                }
            }
            __builtin_amdgcn_s_setprio(0);

            // ---- causal mask (diagonal tile only) ----
            if (t == diag_t) {
                int relq = 32 * (wid & 1) + l31;
                #pragma unroll
                for (int mt = 0; mt < 2; ++mt)
                    #pragma unroll
                    for (int r = 0; r < 16; ++r) {
                        int sl = mt * 32 + (r & 3) + 8 * (r >> 2) + 4 * hi;
                        if (sl > relq) st[mt][r] = -INFINITY;
                    }
            }

            // ---- online softmax (lane-local q; T13 defer-max) ----
            float pmax = -INFINITY;
            #pragma unroll
            for (int mt = 0; mt < 2; ++mt)
                #pragma unroll
                for (int r = 0; r < 16; ++r) pmax = fmaxf(pmax, st[mt][r]);
            pmax = fmaxf(pmax, __shfl_xor(pmax, 32));
            if (!__all(pmax - mrun <= 8.f)) {
                float mnew = fmaxf(mrun, pmax);
                float scl  = __expf(mrun - mnew);
                lrun *= scl;
                #pragma unroll
                for (int mt = 0; mt < 2; ++mt)
                    #pragma unroll
                    for (int r = 0; r < 16; ++r) oacc[mt][r] *= scl;
                mrun = mnew;
            }
            float rsum = 0.f;
            #pragma unroll
            for (int mt = 0; mt < 2; ++mt)
                #pragma unroll
                for (int r = 0; r < 16; ++r) {
                    float p = __expf(st[mt][r] - mrun);
                    st[mt][r] = p;
                    rsum += p;
                }
            rsum += __shfl_xor(rsum, 32);
            lrun += rsum;

            // ---- P -> PV B-frags via packed shfl_xor(32) exchange ----
            bf16x8 pa[4];
            #pragma unroll
            for (int sc = 0; sc < 4; ++sc) {
                const int mt = sc >> 1;
                const int rb = 8 * (sc & 1);        // regs rb..rb+7 = groups rq0, rq1
                unsigned A0 = pk2(st[mt][rb + 0], st[mt][rb + 1]);
                unsigned A1 = pk2(st[mt][rb + 2], st[mt][rb + 3]);
                unsigned B0 = pk2(st[mt][rb + 4], st[mt][rb + 5]);
                unsigned B1 = pk2(st[mt][rb + 6], st[mt][rb + 7]);
                unsigned loc0 = hi ? B0 : A0, loc1 = hi ? B1 : A1;
                unsigned snd0 = hi ? A0 : B0, snd1 = hi ? A1 : B1;
                unsigned rcv0 = __shfl_xor(snd0, 32);
                unsigned rcv1 = __shfl_xor(snd1, 32);
                uint4v w;
                w[0] = hi ? rcv0 : loc0;  w[1] = hi ? rcv1 : loc1;
                w[2] = hi ? loc0 : rcv0;  w[3] = hi ? loc1 : rcv1;
                pa[sc] = __builtin_bit_cast(bf16x8, w);
            }

            // ---- O^T += V^T . P^T ----
            __builtin_amdgcn_s_setprio(1);
            #pragma unroll
            for (int sc = 0; sc < 4; ++sc) {
                #pragma unroll
                for (int mt = 0; mt < 2; ++mt) {
                    int row = mt * 32 + l31;
                    bf16x8 va = *reinterpret_cast<const bf16x8*>(
                        Vb + row * 128 + (((sc * 2 + hi) ^ (l31 & 7)) << 4));
                    oacc[mt] = __builtin_amdgcn_mfma_f32_32x32x16_bf16(va, pa[sc], oacc[mt], 0, 0, 0);
                }
            }
            __builtin_amdgcn_s_setprio(0);
        }
        __syncthreads();
    }
#undef STAGE

    // ---- epilogue: O^T (col=q) -> LDS (granule-swizzled) -> coalesced bf16 store ----
    float linv = 1.f / lrun;
    float* ot = reinterpret_cast<float*>(&smem[0][0][0]) + wid * 2048;   // 32q x 64d per wave
    #pragma unroll
    for (int mt = 0; mt < 2; ++mt)
        #pragma unroll
        for (int r = 0; r < 16; ++r) {
            int d = mt * 32 + (r & 3) + 8 * (r >> 2) + 4 * hi;
            ot[l31 * 64 + (((d >> 2) ^ (l31 & 7)) << 2) + (d & 3)] = oacc[mt][r] * linv;
        }
    // per-wave write->read of own region: compiler orders via lgkmcnt

    const int b = bh >> 4, h = bh & 15;
    const int qrow = lane >> 1;
    const int d0 = (lane & 1) * 32;
    u16 tmp[32];
    #pragma unroll
    for (int i = 0; i < 8; ++i) {
        int g = ((d0 >> 2) + i) ^ (qrow & 7);
        float4 f = *reinterpret_cast<const float4*>(&ot[qrow * 64 + (g << 2)]);
        tmp[i * 4 + 0] = f2bf(f.x); tmp[i * 4 + 1] = f2bf(f.y);
        tmp[i * 4 + 2] = f2bf(f.z); tmp[i * 4 + 3] = f2bf(f.w);
    }
    u16* orow = o + ((size_t)b * T_ + q0 + wid * 32 + qrow) * C_ + h * 64 + d0;
    #pragma unroll
    for (int j = 0; j < 4; ++j)
        *reinterpret_cast<ushort8*>(orow + j * 8) = *reinterpret_cast<ushort8*>(&tmp[j * 8]);
}

extern "C" void kernel_launch(void* const* d_in, const int* in_sizes, int n_in,
                              void* d_out, int out_size, void* d_ws, size_t ws_size,
                              hipStream_t stream) {
    const float* x  = (const float*)d_in[0];
    const float* Wq = (const float*)d_in[1];
    const float* Wk = (const float*)d_in[2];
    const float* Wv = (const float*)d_in[3];
    const float* Wp = (const float*)d_in[4];
    const float* bp = (const float*)d_in[5];
    float* out = (float*)d_out;

    const size_t E = (size_t)M_ * C_;
    u16* xb  = (u16*)d_ws;                   // reused as vT after qkv_gemm
    u16* qb  = xb  + E;
    u16* kb  = qb  + E;
    u16* vb  = kb  + E;
    u16* obf = vb  + E;
    u16* Wt  = obf + E;                      // [3072][1024]
    u16* Wpt = Wt  + (size_t)3072 * 1024;    // [1024][1024]
    u16* vTb = xb;                           // alias: xb dead after qkv_gemm

    cast_x<<<(E / 2048), 256, 0, stream>>>(x, xb);
    tw_qkv<<<dim3(16, 48), 256, 0, stream>>>(Wq, Wk, Wv, Wt);
    tw_p<<<dim3(16, 16), 256, 0, stream>>>(Wp, Wpt);

    qkv_gemm<<<dim3(M_ / 128, 3072 / 128), 256, 0, stream>>>(xb, Wt, qb, kb, vb);

    tv<<<dim3(T_ / 64, B_ * H_), 256, 0, stream>>>(vb, vTb);

    attn_mfma<<<dim3(T_ / 128, B_ * H_), 256, 0, stream>>>(qb, kb, vTb, obf);

    out_gemm<<<dim3(M_ / 128, C_ / 128), 256, 0, stream>>>(obf, Wpt, bp, out);
}

// Round 6
// 178.097 us; speedup vs baseline: 12.0957x; 1.3079x over previous
//
#include <hip/hip_runtime.h>
#include <hip/hip_bf16.h>

// B=4, T=2048, C=1024, H=16, D=64. fp32 in/out.
// cast_x / transpose weights -> qkv_gemm (MFMA 128x128) -> tv (V->V^T) ->
// attn (MFMA 32x32x16 flash, swapped QK^T, O^T form, work-balanced block swizzle) -> out_gemm.

#define B_ 4
#define T_ 2048
#define C_ 1024
#define H_ 16
#define D_ 64
#define M_ (B_*T_)      // 8192

typedef unsigned short u16;
typedef unsigned short ushort8 __attribute__((ext_vector_type(8)));
typedef unsigned int uint4v __attribute__((ext_vector_type(4)));
typedef __attribute__((ext_vector_type(8))) short bf16x8;
typedef __attribute__((ext_vector_type(4))) float f32x4;
typedef __attribute__((ext_vector_type(16))) float f32x16;

__device__ __forceinline__ u16 f2bf(float f) {
    __hip_bfloat16 h = __float2bfloat16(f);
    return *reinterpret_cast<u16*>(&h);
}
__device__ __forceinline__ unsigned pk2(float a, float b) {
    return (unsigned)f2bf(a) | ((unsigned)f2bf(b) << 16);
}

__device__ __forceinline__ void gload_lds16(const void* g, void* lds) {
    __builtin_amdgcn_global_load_lds((const __attribute__((address_space(1))) unsigned int*)g,
                                     (__attribute__((address_space(3))) unsigned int*)lds, 16, 0, 0);
}

// ---------------- cast x -> bf16 ----------------
__global__ __launch_bounds__(256) void cast_x(const float* __restrict__ in, u16* __restrict__ out) {
    int i = (blockIdx.x * 256 + threadIdx.x) * 8;
    float4 a = *reinterpret_cast<const float4*>(in + i);
    float4 b = *reinterpret_cast<const float4*>(in + i + 4);
    ushort8 o;
    o[0]=f2bf(a.x); o[1]=f2bf(a.y); o[2]=f2bf(a.z); o[3]=f2bf(a.w);
    o[4]=f2bf(b.x); o[5]=f2bf(b.y); o[6]=f2bf(b.z); o[7]=f2bf(b.w);
    *reinterpret_cast<ushort8*>(out + i) = o;
}

// ---------------- 64x64 transpose+cast: out[c][r] = in[r][c]*scale ----------------
__device__ __forceinline__ void ttile64(const float* __restrict__ in, int ldin,
                                        u16* __restrict__ out, int ldout, float scale) {
    __shared__ float t[64][65];
    const int tid = threadIdx.x;
    {
        int c = tid & 63, rr = tid >> 6;
        #pragma unroll
        for (int i = 0; i < 16; ++i) {
            int r = i * 4 + rr;
            t[r][c] = in[(size_t)r * ldin + c];
        }
    }
    __syncthreads();
    {
        int r2 = tid & 63, cg = tid >> 6;
        #pragma unroll
        for (int i = 0; i < 16; ++i) {
            int cc = i * 4 + cg;
            out[(size_t)cc * ldout + r2] = f2bf(t[r2][cc] * scale);
        }
    }
}

__global__ __launch_bounds__(256) void tw_qkv(const float* __restrict__ Wq, const float* __restrict__ Wk,
                                              const float* __restrict__ Wv, u16* __restrict__ Wt) {
    const int z = blockIdx.y;
    const int which = z >> 4, h = z & 15;
    const float* W = (which == 0 ? Wq : which == 1 ? Wk : Wv) + (size_t)h * C_ * D_;
    const int r0 = blockIdx.x * 64;
    // fold C^-0.5 AND log2(e) into Wq so softmax uses raw v_exp_f32 (2^x)
    const float scale = (which == 0) ? 0.03125f * 1.4426950408889634f : 1.f;
    ttile64(W + (size_t)r0 * D_, D_, Wt + (size_t)(which * 16 + h) * 64 * C_ + r0, C_, scale);
}

__global__ __launch_bounds__(256) void tw_p(const float* __restrict__ Wp, u16* __restrict__ Wpt) {
    const int r0 = blockIdx.x * 64, c0 = blockIdx.y * 64;
    ttile64(Wp + (size_t)r0 * C_ + c0, C_, Wpt + (size_t)c0 * C_ + r0, C_, 1.f);
}

// ---------------- V [b,h,t,d] -> V^T [b,h,d,t] (bf16) ----------------
__global__ __launch_bounds__(256) void tv(const u16* __restrict__ v, u16* __restrict__ vT) {
    __shared__ u16 t[64][72];
    const int tid = threadIdx.x;
    const int t0 = blockIdx.x * 64, bh = blockIdx.y;
    const u16* src = v + ((size_t)bh * T_ + t0) * D_;
    #pragma unroll
    for (int it = 0; it < 2; ++it) {
        int idx = it * 256 + tid;
        int r = idx >> 3, c8 = (idx & 7) * 8;
        *reinterpret_cast<ushort8*>(&t[r][c8]) =
            *reinterpret_cast<const ushort8*>(src + (size_t)r * D_ + c8);
    }
    __syncthreads();
    #pragma unroll
    for (int it = 0; it < 2; ++it) {
        int idx = it * 256 + tid;
        int d = idx >> 3, c8 = (idx & 7) * 8;
        ushort8 w;
        #pragma unroll
        for (int i = 0; i < 8; ++i) w[i] = t[c8 + i][d];
        *reinterpret_cast<ushort8*>(vT + ((size_t)bh * D_ + d) * T_ + t0 + c8) = w;
    }
}

// ---------------- MFMA GEMM core: 128x128 tile, BK=32, 4 waves, 4x4 frags/wave ----------------
__device__ __forceinline__ void gemm128_core(const u16* __restrict__ A, const u16* __restrict__ Bt,
                                             int m0, int n0, int K,
                                             u16* Asm, u16* Bsm, f32x4 (&acc)[4][4]) {
    const int tid = threadIdx.x;
    const int wid = tid >> 6, lane = tid & 63;
    const int l16 = lane & 15, lq = lane >> 4;
    const int wm = wid >> 1, wn = wid & 1;
    const int srow = lane >> 2;
    const int scol = (lane & 3) * 8;

    for (int k0 = 0; k0 < K; k0 += 32) {
        __syncthreads();
        #pragma unroll
        for (int it = 0; it < 2; ++it) {
            int row = wid * 32 + it * 16 + srow;
            gload_lds16(A  + (size_t)(m0 + row) * K + k0 + scol, Asm + wid * 1024 + it * 512);
            gload_lds16(Bt + (size_t)(n0 + row) * K + k0 + scol, Bsm + wid * 1024 + it * 512);
        }
        __syncthreads();
        bf16x8 af[4], bfr[4];
        #pragma unroll
        for (int t = 0; t < 4; ++t) {
            af[t]  = *reinterpret_cast<const bf16x8*>(Asm + (wm * 64 + t * 16 + l16) * 32 + lq * 8);
            bfr[t] = *reinterpret_cast<const bf16x8*>(Bsm + (wn * 64 + t * 16 + l16) * 32 + lq * 8);
        }
        #pragma unroll
        for (int mt = 0; mt < 4; ++mt)
            #pragma unroll
            for (int nt = 0; nt < 4; ++nt)
                acc[mt][nt] = __builtin_amdgcn_mfma_f32_16x16x32_bf16(af[mt], bfr[nt], acc[mt][nt], 0, 0, 0);
    }
}

// ---------------- QKV GEMM ----------------
__global__ __launch_bounds__(256) void qkv_gemm(const u16* __restrict__ xb, const u16* __restrict__ Wt,
                                                u16* __restrict__ q, u16* __restrict__ k, u16* __restrict__ v) {
    __shared__ u16 Asm[128 * 32], Bsm[128 * 32];
    f32x4 acc[4][4];
    #pragma unroll
    for (int i = 0; i < 4; ++i)
        #pragma unroll
        for (int j = 0; j < 4; ++j) { acc[i][j][0]=0.f; acc[i][j][1]=0.f; acc[i][j][2]=0.f; acc[i][j][3]=0.f; }
    const int m0 = blockIdx.x * 128, n0 = blockIdx.y * 128;
    gemm128_core(xb, Wt, m0, n0, C_, Asm, Bsm, acc);

    const int tid = threadIdx.x, wid = tid >> 6, lane = tid & 63;
    const int l16 = lane & 15, lq = lane >> 4;
    const int wm = wid >> 1, wn = wid & 1;
    #pragma unroll
    for (int mt = 0; mt < 4; ++mt) {
        #pragma unroll
        for (int j = 0; j < 4; ++j) {
            int m = m0 + wm * 64 + mt * 16 + lq * 4 + j;
            int b = m >> 11, t = m & (T_ - 1);
            #pragma unroll
            for (int nt = 0; nt < 4; ++nt) {
                int n = n0 + wn * 64 + nt * 16 + l16;
                int which = n >> 10, h = (n >> 6) & 15, d = n & 63;
                u16* dst = (which == 0 ? q : which == 1 ? k : v);
                dst[((size_t)(b * H_ + h) * T_ + t) * D_ + d] = f2bf(acc[mt][nt][j]);
            }
        }
    }
}

// ---------------- Output GEMM ----------------
__global__ __launch_bounds__(256) void out_gemm(const u16* __restrict__ ob, const u16* __restrict__ Wpt,
                                                const float* __restrict__ bp, float* __restrict__ out) {
    __shared__ u16 Asm[128 * 32], Bsm[128 * 32];
    f32x4 acc[4][4];
    #pragma unroll
    for (int i = 0; i < 4; ++i)
        #pragma unroll
        for (int j = 0; j < 4; ++j) { acc[i][j][0]=0.f; acc[i][j][1]=0.f; acc[i][j][2]=0.f; acc[i][j][3]=0.f; }
    const int m0 = blockIdx.x * 128, n0 = blockIdx.y * 128;
    gemm128_core(ob, Wpt, m0, n0, C_, Asm, Bsm, acc);

    const int tid = threadIdx.x, wid = tid >> 6, lane = tid & 63;
    const int l16 = lane & 15, lq = lane >> 4;
    const int wm = wid >> 1, wn = wid & 1;
    #pragma unroll
    for (int mt = 0; mt < 4; ++mt) {
        #pragma unroll
        for (int j = 0; j < 4; ++j) {
            int m = m0 + wm * 64 + mt * 16 + lq * 4 + j;
            #pragma unroll
            for (int nt = 0; nt < 4; ++nt) {
                int n = n0 + wn * 64 + nt * 16 + l16;
                out[(size_t)m * C_ + n] = acc[mt][nt][j] + bp[n];
            }
        }
    }
}

// ---------------- MFMA flash attention v4: 32x32x16, QBLK=128, O^T, balanced swizzle ----------------
// 1D grid 1024. r=lin&255 models CU slot (8 XCD x 32 CU), f=lin>>8 the 4 rounds per CU.
// qb per round = {e, e+8, 15-e, 7-e} (e=r&7): per-CU tile-work = 2*30+8 = 68, constant.
__global__ __launch_bounds__(256) void attn_mfma(const u16* __restrict__ q,
                                                 const u16* __restrict__ k,
                                                 const u16* __restrict__ vT,
                                                 u16* __restrict__ o) {
    __shared__ u16 smem[2][2][4096];   // [K|V][dbuf][64x64 tile], 32 KiB

    const int tid  = threadIdx.x;
    const int wid  = tid >> 6;
    const int lane = tid & 63;
    const int l31  = lane & 31;
    const int hi   = lane >> 5;

    // ---- work-balanced bijective (qb, bh) decode ----
    const int lin = blockIdx.x;
    const int r   = lin & 255;
    const int f   = lin >> 8;           // 0..3
    const int e   = r & 7;
    int qb, bh;
    if      (f == 0) { qb = e;      bh = (r >> 3);      }
    else if (f == 1) { qb = e + 8;  bh = (r >> 3) + 32; }
    else if (f == 2) { qb = 15 - e; bh = (r >> 3);      }
    else             { qb = 7 - e;  bh = (r >> 3) + 32; }

    const int q0   = qb * 128;
    const size_t base = (size_t)bh * T_ * D_;
    const u16* kp  = k  + base;
    const u16* vtp = vT + (size_t)bh * D_ * T_;
    const int qglob = q0 + wid * 32 + l31;

    // Q B-frags: col=l31=q, k = kc*16 + hi*8 + i
    bf16x8 qf[4];
    {
        const u16* qp = q + base + (size_t)qglob * D_;
        #pragma unroll
        for (int kc = 0; kc < 4; ++kc)
            qf[kc] = *reinterpret_cast<const bf16x8*>(qp + kc * 16 + hi * 8);
    }

    float mrun = -INFINITY, lrun = 0.f;
    f32x16 oacc[2];                                 // O^T: col=q(=l31), row d = mt*32+(r&3)+8*(r>>2)+4*hi
    #pragma unroll
    for (int mt = 0; mt < 2; ++mt)
        #pragma unroll
        for (int rr = 0; rr < 16; ++rr) oacc[mt][rr] = 0.f;

    const int ntile  = 2 * qb + 2;
    const int diag_t = 2 * qb + (wid >> 1);

#define STAGE(buf, s0b)                                                              \
    {                                                                                \
        _Pragma("unroll")                                                            \
        for (int it = 0; it < 2; ++it) {                                             \
            int g = it * 256 + wid * 64 + lane;                                      \
            int rw = g >> 3, cg = (g & 7) ^ (rw & 7);                                \
            gload_lds16(kp + (size_t)(s0b + rw) * D_ + cg * 8,                       \
                        &smem[0][buf][(it * 256 + wid * 64) * 8]);                   \
            gload_lds16(vtp + (size_t)rw * T_ + (s0b) + cg * 8,                      \
                        &smem[1][buf][(it * 256 + wid * 64) * 8]);                   \
        }                                                                            \
    }

    STAGE(0, 0);
    __syncthreads();

    for (int t = 0; t < ntile; ++t) {
        const int cur = t & 1;
        if (t + 1 < ntile) STAGE(cur ^ 1, (t + 1) * 64);

        if (t <= diag_t) {                          // wave-uniform skip of fully-masked tiles
            const char* Kb = reinterpret_cast<const char*>(&smem[0][cur][0]);
            const char* Vb = reinterpret_cast<const char*>(&smem[1][cur][0]);

            // ---- S^T = K . Q  (S' pre-scaled by log2e/32 via Wq) ----
            f32x16 st[2];
            #pragma unroll
            for (int mt = 0; mt < 2; ++mt)
                #pragma unroll
                for (int rr = 0; rr < 16; ++rr) st[mt][rr] = 0.f;
            __builtin_amdgcn_s_setprio(1);
            #pragma unroll
            for (int kc = 0; kc < 4; ++kc) {
                #pragma unroll
                for (int mt = 0; mt < 2; ++mt) {
                    int row = mt * 32 + l31;
                    bf16x8 ka = *reinterpret_cast<const bf16x8*>(
                        Kb + row * 128 + (((kc * 2 + hi) ^ (l31 & 7)) << 4));
                    st[mt] = __builtin_amdgcn_mfma_f32_32x32x16_bf16(ka, qf[kc], st[mt], 0, 0, 0);
                }
            }
            __builtin_amdgcn_s_setprio(0);

            // ---- causal mask (diagonal tile only) ----
            if (t == diag_t) {
                int relq = 32 * (wid & 1) + l31;
                #pragma unroll
                for (int mt = 0; mt < 2; ++mt)
                    #pragma unroll
                    for (int rr = 0; rr < 16; ++rr) {
                        int sl = mt * 32 + (rr & 3) + 8 * (rr >> 2) + 4 * hi;
                        if (sl > relq) st[mt][rr] = -INFINITY;
                    }
            }

            // ---- online softmax base-2 (lane-local q; T13 defer-max, thr = 8*log2e) ----
            float pmax = -INFINITY;
            #pragma unroll
            for (int mt = 0; mt < 2; ++mt)
                #pragma unroll
                for (int rr = 0; rr < 16; ++rr) pmax = fmaxf(pmax, st[mt][rr]);
            pmax = fmaxf(pmax, __shfl_xor(pmax, 32));
            if (!__all(pmax - mrun <= 11.54f)) {
                float mnew = fmaxf(mrun, pmax);
                float scl  = __builtin_amdgcn_exp2f(mrun - mnew);
                lrun *= scl;
                #pragma unroll
                for (int mt = 0; mt < 2; ++mt)
                    #pragma unroll
                    for (int rr = 0; rr < 16; ++rr) oacc[mt][rr] *= scl;
                mrun = mnew;
            }
            float rsum = 0.f;
            #pragma unroll
            for (int mt = 0; mt < 2; ++mt)
                #pragma unroll
                for (int rr = 0; rr < 16; ++rr) {
                    float p = __builtin_amdgcn_exp2f(st[mt][rr] - mrun);
                    st[mt][rr] = p;
                    rsum += p;
                }
            rsum += __shfl_xor(rsum, 32);
            lrun += rsum;

            // ---- P -> PV B-frags via packed shfl_xor(32) exchange ----
            bf16x8 pa[4];
            #pragma unroll
            for (int sc = 0; sc < 4; ++sc) {
                const int mt = sc >> 1;
                const int rb = 8 * (sc & 1);
                unsigned A0 = pk2(st[mt][rb + 0], st[mt][rb + 1]);
                unsigned A1 = pk2(st[mt][rb + 2], st[mt][rb + 3]);
                unsigned B0 = pk2(st[mt][rb + 4], st[mt][rb + 5]);
                unsigned B1 = pk2(st[mt][rb + 6], st[mt][rb + 7]);
                unsigned loc0 = hi ? B0 : A0, loc1 = hi ? B1 : A1;
                unsigned snd0 = hi ? A0 : B0, snd1 = hi ? A1 : B1;
                unsigned rcv0 = __shfl_xor(snd0, 32);
                unsigned rcv1 = __shfl_xor(snd1, 32);
                uint4v w;
                w[0] = hi ? rcv0 : loc0;  w[1] = hi ? rcv1 : loc1;
                w[2] = hi ? loc0 : rcv0;  w[3] = hi ? loc1 : rcv1;
                pa[sc] = __builtin_bit_cast(bf16x8, w);
            }

            // ---- O^T += V^T . P^T ----
            __builtin_amdgcn_s_setprio(1);
            #pragma unroll
            for (int sc = 0; sc < 4; ++sc) {
                #pragma unroll
                for (int mt = 0; mt < 2; ++mt) {
                    int row = mt * 32 + l31;
                    bf16x8 va = *reinterpret_cast<const bf16x8*>(
                        Vb + row * 128 + (((sc * 2 + hi) ^ (l31 & 7)) << 4));
                    oacc[mt] = __builtin_amdgcn_mfma_f32_32x32x16_bf16(va, pa[sc], oacc[mt], 0, 0, 0);
                }
            }
            __builtin_amdgcn_s_setprio(0);
        }
        __syncthreads();
    }
#undef STAGE

    // ---- epilogue: O^T (col=q) -> LDS (granule-swizzled) -> coalesced bf16 store ----
    float linv = 1.f / lrun;
    float* ot = reinterpret_cast<float*>(&smem[0][0][0]) + wid * 2048;   // 32q x 64d per wave
    #pragma unroll
    for (int mt = 0; mt < 2; ++mt)
        #pragma unroll
        for (int rr = 0; rr < 16; ++rr) {
            int d = mt * 32 + (rr & 3) + 8 * (rr >> 2) + 4 * hi;
            ot[l31 * 64 + (((d >> 2) ^ (l31 & 7)) << 2) + (d & 3)] = oacc[mt][rr] * linv;
        }
    // per-wave write->read of own region: compiler orders via lgkmcnt

    const int b = bh >> 4, h = bh & 15;
    const int qrow = lane >> 1;
    const int d0 = (lane & 1) * 32;
    u16 tmp[32];
    #pragma unroll
    for (int i = 0; i < 8; ++i) {
        int g = ((d0 >> 2) + i) ^ (qrow & 7);
        float4 fv = *reinterpret_cast<const float4*>(&ot[qrow * 64 + (g << 2)]);
        tmp[i * 4 + 0] = f2bf(fv.x); tmp[i * 4 + 1] = f2bf(fv.y);
        tmp[i * 4 + 2] = f2bf(fv.z); tmp[i * 4 + 3] = f2bf(fv.w);
    }
    u16* orow = o + ((size_t)b * T_ + q0 + wid * 32 + qrow) * C_ + h * 64 + d0;
    #pragma unroll
    for (int j = 0; j < 4; ++j)
        *reinterpret_cast<ushort8*>(orow + j * 8) = *reinterpret_cast<ushort8*>(&tmp[j * 8]);
}

extern "C" void kernel_launch(void* const* d_in, const int* in_sizes, int n_in,
                              void* d_out, int out_size, void* d_ws, size_t ws_size,
                              hipStream_t stream) {
    const float* x  = (const float*)d_in[0];
    const float* Wq = (const float*)d_in[1];
    const float* Wk = (const float*)d_in[2];
    const float* Wv = (const float*)d_in[3];
    const float* Wp = (const float*)d_in[4];
    const float* bp = (const float*)d_in[5];
    float* out = (float*)d_out;

    const size_t E = (size_t)M_ * C_;
    u16* xb  = (u16*)d_ws;                   // reused as vT after qkv_gemm
    u16* qb  = xb  + E;
    u16* kb  = qb  + E;
    u16* vb  = kb  + E;
    u16* obf = vb  + E;
    u16* Wt  = obf + E;                      // [3072][1024]
    u16* Wpt = Wt  + (size_t)3072 * 1024;    // [1024][1024]
    u16* vTb = xb;                           // alias: xb dead after qkv_gemm

    cast_x<<<(E / 2048), 256, 0, stream>>>(x, xb);
    tw_qkv<<<dim3(16, 48), 256, 0, stream>>>(Wq, Wk, Wv, Wt);
    tw_p<<<dim3(16, 16), 256, 0, stream>>>(Wp, Wpt);

    qkv_gemm<<<dim3(M_ / 128, 3072 / 128), 256, 0, stream>>>(xb, Wt, qb, kb, vb);

    tv<<<dim3(T_ / 64, B_ * H_), 256, 0, stream>>>(vb, vTb);

    attn_mfma<<<dim3(1024), 256, 0, stream>>>(qb, kb, vTb, obf);

    out_gemm<<<dim3(M_ / 128, C_ / 128), 256, 0, stream>>>(obf, Wpt, bp, out);
}